// Round 8
// baseline (359.264 us; speedup 1.0000x reference)
//
#include <hip/hip_runtime.h>

#define SEQ   2048
#define BATCH 2
#define HID   2048
#define NHEAD 16
#define HDIM  128
#define MTOT  4096
#define KDIM  2048

typedef __attribute__((ext_vector_type(8))) short  bf16x8;
typedef __attribute__((ext_vector_type(4))) float  f32x4;
typedef __attribute__((ext_vector_type(4))) unsigned short u16x4;
typedef __attribute__((ext_vector_type(8))) unsigned short u16x8;

__device__ __forceinline__ unsigned short f2bf(float x) {
  unsigned u = __float_as_uint(x);
  u += 0x7fffu + ((u >> 16) & 1u);
  return (unsigned short)(u >> 16);
}

__device__ __forceinline__ float fexp2(float x) {
  float r;
  asm("v_exp_f32 %0, %1" : "=v"(r) : "v"(x));
  return r;
}

__device__ __forceinline__ void gl_lds16(const void* g, void* l) {
  __builtin_amdgcn_global_load_lds(
      (__attribute__((address_space(1))) void*)g,
      (__attribute__((address_space(3))) void*)l, 16, 0, 0);
}

__device__ __forceinline__ f32x4 mfma16(bf16x8 a, bf16x8 b, f32x4 c) {
  return __builtin_amdgcn_mfma_f32_16x16x32_bf16(a, b, c, 0, 0, 0);
}

// ---------------------------------------------------------------------------
// Fused prep: fp32->bf16. hidden -> PLAIN row-major (read direct-to-reg by
// gemm_qkv). Weights -> K-granule swizzle (k ^ (((r>>1)&3)<<3)) for the
// gl_lds->LDS->ds_read_b128 path. + RoPE cos/sin table.
// ---------------------------------------------------------------------------
__global__ __launch_bounds__(256, 8)
void prep(const float* __restrict__ hidden, const float* __restrict__ Wqkv,
          const float* __restrict__ Wd,
          unsigned short* __restrict__ hidb, unsigned short* __restrict__ wqkvb,
          unsigned short* __restrict__ wdb,
          float* __restrict__ cosT, float* __restrict__ sinT) {
  int bid = blockIdx.x;
  if (bid < 24576) {
    const float* src; unsigned short* dst; int lb; bool swz;
    if (bid < 8192)       { src = hidden; dst = hidb;  lb = bid;         swz = false; }
    else if (bid < 20480) { src = Wqkv;   dst = wqkvb; lb = bid - 8192;  swz = true; }
    else                  { src = Wd;     dst = wdb;   lb = bid - 20480; swz = true; }
    int i = lb * 256 + threadIdx.x;
    int base = i << 2;
    int r = base >> 11, k = base & 2047;
    f32x4 v = *(const f32x4*)(src + base);
    int kp = swz ? (k ^ (((r >> 1) & 3) << 3)) : k;
    u16x4 o;
    o[0] = f2bf(v[0]); o[1] = f2bf(v[1]); o[2] = f2bf(v[2]); o[3] = f2bf(v[3]);
    *(u16x4*)(dst + (size_t)r * 2048 + kp) = o;
  } else {
    int idx = (bid - 24576) * 256 + threadIdx.x;   // 2048*64
    int s = idx >> 6, i = idx & 63;
    float inv = powf(1e-4f, (float)i * (1.0f / 64.0f));
    float a = (float)s * inv;
    cosT[idx] = cosf(a);
    sinT[idx] = sinf(a);
  }
}

// ---------------------------------------------------------------------------
// QKV GEMM: 128x384 tile, BK=32, grid 512 = 2 full rounds, 8 waves = 2M x 4N.
// A-OPERAND BYPASSES LDS: per-lane direct global->VGPR loads (row-major hidb),
// double-prefetched 2 tiles ahead into 3 named reg sets. B stays LDS ring-3
// (24KB/buf, 72 KiB total). Per tile: 3 B-stage gl_lds + 4 A-loads = 7 vm ops;
// end-of-tile vmcnt(7) drains exactly tile T+1's B-stage and A-regs.
// B-frags ds_read issued after the barrier (consumed NEXT tile), drained by
// lgkmcnt(0)+sched_barrier(0) at tile start (rule: compiler hoists reg-only
// MFMA past inline-asm lgkmcnt otherwise).
// LDS traffic/tile = 72KB (was 114KB) -> below the MFMA pipe's 931 cyc.
// ---------------------------------------------------------------------------
__global__ __launch_bounds__(512, 2)
void gemm_qkv(const unsigned short* __restrict__ A,
              const unsigned short* __restrict__ Bt,
              const float* __restrict__ bias,
              unsigned short* __restrict__ Qs,
              unsigned short* __restrict__ Ks,
              unsigned short* __restrict__ Vp,
              const float* __restrict__ cosT,
              const float* __restrict__ sinT)
{
  __shared__ alignas(16) char lds[73728];   // B ring-3: 3 x 24KB
  const int tid = threadIdx.x;
  const int wid = tid >> 6, lane = tid & 63, g = lane >> 4, c = lane & 15;
  const int wr = wid >> 2, wc = wid & 3;

  // XCD swizzle: XCD x -> mblk [x*4,x*4+4), all 16 nblk (A panels L2-resident)
  const int bid = blockIdx.x;
  const int swz = (bid & 7) * 64 + (bid >> 3);
  const int nblk = swz & 15, mblk = swz >> 4;
  const int m0 = mblk << 7;
  const int n0 = nblk * 384;
  const int nh = nblk;

  char* ldsb = (char*)lds;
  const int slotg = (g ^ ((c >> 1) & 3)) << 4;
  const char* ldsBr = ldsb + (wc * 16 + c) * 64 + slotg;

  const char* gA2 = (const char*)A + (size_t)(m0 + wr * 64 + c) * 4096 + g * 16;
  const char* gB = (const char*)Bt + (size_t)(n0 + (tid >> 2)) * 4096 + (tid & 3) * 16;
  char* lB = ldsb + tid * 16;

#define STG_B(T, BUF) do { const char* _g = gB + (T) * 64; char* _l = lB + (BUF) * 24576; \
    gl_lds16(_g, _l); gl_lds16(_g + 524288, _l + 8192); gl_lds16(_g + 1048576, _l + 16384); } while (0)
#define A_LOAD(T, AR) do { const char* _g = gA2 + (T) * 64;                  \
    _Pragma("unroll")                                                        \
    for (int mf = 0; mf < 4; ++mf)                                           \
      AR[mf] = *(const bf16x8*)(_g + mf * 65536); } while (0)
#define FRAG_B(BUF) do { _Pragma("unroll")                                   \
    for (int nl = 0; nl < 6; ++nl)                                           \
      b[nl] = *(const bf16x8*)(ldsBr + (BUF) * 24576 + nl * 4096); } while (0)

  f32x4 acc[4][6];
#pragma unroll
  for (int i = 0; i < 4; ++i)
#pragma unroll
    for (int j = 0; j < 6; ++j) {
      acc[i][j][0] = 0.f; acc[i][j][1] = 0.f; acc[i][j][2] = 0.f; acc[i][j][3] = 0.f;
    }

  bf16x8 a0[4], a1[4], a2[4], b[6];
  const int NT = KDIM / 32;   // 64

  // TILE T: stage B(T+2), load A(T+2); MFMA(T) on regs; vmcnt(7) drains
  // B(T+1)+A(T+1); barrier; ds_read B-frags(T+1).
#define TILEQ(T, BUFS, BUFR, AC, AN) do {                                    \
    if ((T) + 2 < NT) { STG_B((T) + 2, BUFS); A_LOAD((T) + 2, AN); }         \
    asm volatile("s_waitcnt lgkmcnt(0)" ::: "memory");                       \
    __builtin_amdgcn_sched_barrier(0);                                       \
    __builtin_amdgcn_s_setprio(1);                                           \
    _Pragma("unroll")                                                        \
    for (int mf = 0; mf < 4; ++mf)                                           \
      _Pragma("unroll")                                                      \
      for (int nl = 0; nl < 6; ++nl)                                         \
        acc[mf][nl] = mfma16(AC[mf], b[nl], acc[mf][nl]);                    \
    __builtin_amdgcn_s_setprio(0);                                           \
    if ((T) + 2 < NT) { asm volatile("s_waitcnt vmcnt(7)" ::: "memory"); }   \
    else              { asm volatile("s_waitcnt vmcnt(0)" ::: "memory"); }   \
    __builtin_amdgcn_s_barrier();                                            \
    if ((T) + 1 < NT) { FRAG_B(BUFR); }                                      \
  } while (0)

  // Prologue: issue B(0),A(0),B(1),A(1) = 14 ops; vmcnt(7) drains B(0)+A(0).
  STG_B(0, 0); A_LOAD(0, a0);
  STG_B(1, 1); A_LOAD(1, a1);
  asm volatile("s_waitcnt vmcnt(7)" ::: "memory");
  __builtin_amdgcn_s_barrier();
  FRAG_B(0);

  for (int t = 0; t < 63; t += 3) {
    TILEQ(t,     2, 1, a0, a2);
    TILEQ(t + 1, 0, 2, a1, a0);
    TILEQ(t + 2, 1, 0, a2, a1);
  }
  TILEQ(63, 2, 1, a0, a2);

  // ---- epilogue: bias + RoPE; nl pairs (0,1)=Q, (2,3)=K, (4,5)=V ----
  const float qsc = 0.08838834764831845f * 1.4426950408889634f; // 1/sqrt(128)*log2(e)
  const int dl = wc * 16 + c;   // 0..63
#pragma unroll
  for (int ar = 0; ar < 4; ++ar) {
#pragma unroll
    for (int rr = 0; rr < 4; ++rr) {
      int m = m0 + wr * 64 + ar * 16 + g * 4 + rr;
      int s = m >> 1, bb = m & 1;
      size_t plane = (size_t)(bb * NHEAD + nh) * (SEQ * HDIM);
      int swb = (s & 7) << 3;
      float co = cosT[s * 64 + dl], si = sinT[s * 64 + dl];
      {
        float xl = acc[ar][0][rr] + bias[n0 + dl];
        float xr = acc[ar][1][rr] + bias[n0 + 64 + dl];
        Qs[plane + (size_t)s * HDIM + (dl ^ swb)]        = f2bf((co * xl - si * xr) * qsc);
        Qs[plane + (size_t)s * HDIM + ((dl + 64) ^ swb)] = f2bf((si * xl + co * xr) * qsc);
      }
      {
        float xl = acc[ar][2][rr] + bias[n0 + 128 + dl];
        float xr = acc[ar][3][rr] + bias[n0 + 192 + dl];
        Ks[plane + (size_t)s * HDIM + (dl ^ swb)]        = f2bf(co * xl - si * xr);
        Ks[plane + (size_t)s * HDIM + ((dl + 64) ^ swb)] = f2bf(si * xl + co * xr);
      }
      Vp[plane + (size_t)s * HDIM + dl]      = f2bf(acc[ar][4][rr] + bias[n0 + 256 + dl]);
      Vp[plane + (size_t)s * HDIM + dl + 64] = f2bf(acc[ar][5][rr] + bias[n0 + 320 + dl]);
    }
  }
#undef TILEQ
#undef FRAG_B
#undef A_LOAD
#undef STG_B
}

// ---------------------------------------------------------------------------
// Dense projection: 128x256 tile, grid 256 = 1 round. A (ctx, plain rows)
// direct-to-reg; B (Wd swizzled) LDS ring-3. 6 vm ops/tile -> vmcnt(6).
// ---------------------------------------------------------------------------
__global__ __launch_bounds__(512, 2)
void gemm_out(const unsigned short* __restrict__ A,
              const unsigned short* __restrict__ Bt,
              const float* __restrict__ bias,
              float* __restrict__ Cout)
{
  __shared__ alignas(16) char lds[49152];   // B ring-3: 3 x 16KB
  const int tid = threadIdx.x;
  const int wid = tid >> 6, lane = tid & 63, g = lane >> 4, c = lane & 15;
  const int wr = wid >> 2, wc = wid & 3;

  const int bid = blockIdx.x;
  const int swz = (bid & 7) * 32 + (bid >> 3);
  const int nblk = swz >> 5, mblk = swz & 31;
  const int m0 = mblk << 7, n0 = nblk << 8;

  char* ldsb = (char*)lds;
  const int slotg = (g ^ ((c >> 1) & 3)) << 4;
  const char* ldsBr = ldsb + (wc * 64 + c) * 64 + slotg;

  const char* gA2 = (const char*)A + (size_t)(m0 + wr * 64 + c) * 4096 + g * 16;
  const char* gB = (const char*)Bt + (size_t)(n0 + (tid >> 2)) * 4096 + (tid & 3) * 16;
  char* lB = ldsb + tid * 16;

#define STG_B(T, BUF) do { const char* _g = gB + (T) * 64; char* _l = lB + (BUF) * 16384; \
    gl_lds16(_g, _l); gl_lds16(_g + 524288, _l + 8192); } while (0)
#define A_LOAD(T, AR) do { const char* _g = gA2 + (T) * 64;                  \
    _Pragma("unroll")                                                        \
    for (int mf = 0; mf < 4; ++mf)                                           \
      AR[mf] = *(const bf16x8*)(_g + mf * 65536); } while (0)
#define FRAG_B(BUF) do { _Pragma("unroll")                                   \
    for (int nl = 0; nl < 4; ++nl)                                           \
      b[nl] = *(const bf16x8*)(ldsBr + (BUF) * 16384 + nl * 1024); } while (0)

  f32x4 acc[4][4];
#pragma unroll
  for (int i = 0; i < 4; ++i)
#pragma unroll
    for (int j = 0; j < 4; ++j) {
      acc[i][j][0] = 0.f; acc[i][j][1] = 0.f; acc[i][j][2] = 0.f; acc[i][j][3] = 0.f;
    }

  bf16x8 a0[4], a1[4], a2[4], b[4];
  const int NT = KDIM / 32;   // 64

#define TILEO(T, BUFS, BUFR, AC, AN) do {                                    \
    if ((T) + 2 < NT) { STG_B((T) + 2, BUFS); A_LOAD((T) + 2, AN); }         \
    asm volatile("s_waitcnt lgkmcnt(0)" ::: "memory");                       \
    __builtin_amdgcn_sched_barrier(0);                                       \
    __builtin_amdgcn_s_setprio(1);                                           \
    _Pragma("unroll")                                                        \
    for (int mf = 0; mf < 4; ++mf)                                           \
      _Pragma("unroll")                                                      \
      for (int nl = 0; nl < 4; ++nl)                                         \
        acc[mf][nl] = mfma16(AC[mf], b[nl], acc[mf][nl]);                    \
    __builtin_amdgcn_s_setprio(0);                                           \
    if ((T) + 2 < NT) { asm volatile("s_waitcnt vmcnt(6)" ::: "memory"); }   \
    else              { asm volatile("s_waitcnt vmcnt(0)" ::: "memory"); }   \
    __builtin_amdgcn_s_barrier();                                            \
    if ((T) + 1 < NT) { FRAG_B(BUFR); }                                      \
  } while (0)

  STG_B(0, 0); A_LOAD(0, a0);
  STG_B(1, 1); A_LOAD(1, a1);
  asm volatile("s_waitcnt vmcnt(6)" ::: "memory");
  __builtin_amdgcn_s_barrier();
  FRAG_B(0);

  for (int t = 0; t < 63; t += 3) {
    TILEO(t,     2, 1, a0, a2);
    TILEO(t + 1, 0, 2, a1, a0);
    TILEO(t + 2, 1, 0, a2, a1);
  }
  TILEO(63, 2, 1, a0, a2);

#pragma unroll
  for (int mf = 0; mf < 4; ++mf)
#pragma unroll
    for (int rr = 0; rr < 4; ++rr) {
      int m = m0 + wr * 64 + mf * 16 + g * 4 + rr;
#pragma unroll
      for (int nl = 0; nl < 4; ++nl) {
        int n = n0 + wc * 64 + nl * 16 + c;
        Cout[(size_t)m * HID + n] = acc[mf][nl][rr] + bias[n];
      }
    }
#undef TILEO
#undef FRAG_B
#undef A_LOAD
#undef STG_B
}

// V [plane][t][d] -> Vt [plane][d][t], t-granule swizzled: (t ^ ((d&7)<<3))
__global__ __launch_bounds__(256, 4)
void transpose_v(const unsigned short* __restrict__ Vp, unsigned short* __restrict__ Vt) {
  __shared__ alignas(16) unsigned short T[64 * 136];
  const int plane = blockIdx.x >> 5;
  const int t0 = (blockIdx.x & 31) << 6;
  const size_t pbase = (size_t)plane * (SEQ * HDIM);
  const int tid = threadIdx.x;
  {
    int t = tid >> 2, d0 = (tid & 3) << 5;
    const unsigned short* src = Vp + pbase + (size_t)(t0 + t) * HDIM + d0;
#pragma unroll
    for (int j = 0; j < 4; ++j) {
      u16x8 v = *(const u16x8*)(src + j * 8);
      *(u16x8*)(&T[t * 136 + d0 + j * 8]) = v;
    }
  }
  __syncthreads();
  {
    int d = tid >> 1, half = tid & 1;
    unsigned short* dstp = Vt + pbase + (size_t)d * SEQ;
    int swb = (d & 7) << 3;
#pragma unroll
    for (int gg = 0; gg < 4; ++gg) {
      u16x8 v;
#pragma unroll
      for (int e = 0; e < 8; ++e)
        v[e] = T[(half * 32 + gg * 8 + e) * 136 + d];
      int tloc = half * 32 + gg * 8;
      *(u16x8*)(dstp + ((t0 + tloc) ^ swb)) = v;
    }
  }
}

// ---------------------------------------------------------------------------
// Flash attention (ctx now written UNSWIZZLED for gemm_out's direct A-loads)
// ---------------------------------------------------------------------------
__global__ __launch_bounds__(256, 2)
void attn(const unsigned short* __restrict__ Qs,
          const unsigned short* __restrict__ Ks,
          const unsigned short* __restrict__ Vt,
          unsigned short* __restrict__ ctx)
{
  __shared__ alignas(16) unsigned short Klds[2][64 * 128];
  __shared__ alignas(16) unsigned short Vlds[128 * 64];
  __shared__ alignas(16) unsigned short Plds[128 * 72];
  const int tid = threadIdx.x;
  const int w = tid >> 6, lane = tid & 63, g = lane >> 4, c = lane & 15;
  const int bid = blockIdx.x;
  const int head = bid & 31;
  const int qb = (bid < 256) ? (15 - (bid >> 5)) : ((bid >> 5) - 8);
  const int q0 = qb << 7;
  const size_t plane = (size_t)head * (SEQ * HDIM);
  const unsigned short* Qp = Qs + plane;
  const unsigned short* Kp = Ks + plane;
  const unsigned short* Vp = Vt + plane;

  bf16x8 qf[2][4];
#pragma unroll
  for (int q2 = 0; q2 < 2; ++q2) {
    int s = q0 + w * 32 + q2 * 16 + c;
    int swb = (s & 7) << 3;
#pragma unroll
    for (int kk = 0; kk < 4; ++kk) {
      int d0 = kk * 32 + g * 8;
      qf[q2][kk] = *(const bf16x8*)(Qp + (size_t)s * HDIM + (d0 ^ swb));
    }
  }

  f32x4 accO[2][8];
#pragma unroll
  for (int i = 0; i < 2; ++i)
#pragma unroll
    for (int j = 0; j < 8; ++j) {
      accO[i][j][0] = 0.f; accO[i][j][1] = 0.f; accO[i][j][2] = 0.f; accO[i][j][3] = 0.f;
    }
  float mrun[2] = { -1e30f, -1e30f };
  float lrun[2] = { 0.f, 0.f };

  const char* KgBase = (const char*)Kp + (tid >> 4) * 256 + (tid & 15) * 16;
  const char* VgBase = (const char*)Vp + (size_t)(tid >> 3) * 4096 + (tid & 7) * 16;
  char* VldsW = (char*)Vlds + w * 1024;

  const int ntiles = (q0 >> 6) + 2;
  const int qminw = q0 + w * 32;
  const int qmaxw = qminw + 31;

#pragma unroll
  for (int i = 0; i < 4; ++i)
    gl_lds16(KgBase, (char*)Klds[0] + w * 1024 + i * 4096), KgBase += 4096;
  KgBase -= 16384;

  for (int kt = 0; kt < ntiles; ++kt) {
    const int t0 = kt << 6;
    const bool havenext = (kt + 1 < ntiles);

#pragma unroll
    for (int i = 0; i < 4; ++i)
      gl_lds16(VgBase + t0 * 2 + (size_t)i * 131072, VldsW + i * 4096);
    if (havenext) {
      char* kdst = (char*)Klds[(kt + 1) & 1] + w * 1024;
#pragma unroll
      for (int i = 0; i < 4; ++i)
        gl_lds16(KgBase + (size_t)(t0 + 64) * 256 + i * 4096, kdst + i * 4096);
    }
    if (havenext) asm volatile("s_waitcnt vmcnt(8)" ::: "memory");
    else          asm volatile("s_waitcnt vmcnt(4)" ::: "memory");
    __builtin_amdgcn_s_barrier();

    if (t0 <= qmaxw) {
      const char* Kb = (const char*)Klds[kt & 1];
      f32x4 sacc[4][2];
#pragma unroll
      for (int i = 0; i < 4; ++i)
#pragma unroll
        for (int j = 0; j < 2; ++j) {
          sacc[i][j][0] = 0.f; sacc[i][j][1] = 0.f; sacc[i][j][2] = 0.f; sacc[i][j][3] = 0.f;
        }
      __builtin_amdgcn_s_setprio(1);
#pragma unroll
      for (int kk = 0; kk < 4; ++kk) {
        bf16x8 kf[4];
#pragma unroll
        for (int ta = 0; ta < 4; ++ta) {
          int t = ta * 16 + c;
          int d0 = kk * 32 + g * 8;
          kf[ta] = *(const bf16x8*)(Kb + t * 256 + ((d0 ^ ((t & 7) << 3)) << 1));
        }
#pragma unroll
        for (int ta = 0; ta < 4; ++ta)
#pragma unroll
          for (int q2 = 0; q2 < 2; ++q2)
            sacc[ta][q2] = mfma16(kf[ta], qf[q2][kk], sacc[ta][q2]);
      }
      __builtin_amdgcn_s_setprio(0);

      if (t0 + 63 > qminw) {
#pragma unroll
        for (int ta = 0; ta < 4; ++ta)
#pragma unroll
          for (int q2 = 0; q2 < 2; ++q2)
#pragma unroll
            for (int r = 0; r < 4; ++r) {
              int t = t0 + ta * 16 + g * 4 + r;
              int q = qminw + q2 * 16 + c;
              if (t > q) sacc[ta][q2][r] = -30000.f;
            }
      }

      float corr[2];
      bool resc = false;
#pragma unroll
      for (int q2 = 0; q2 < 2; ++q2) {
        float mx = -30000.f;
#pragma unroll
        for (int ta = 0; ta < 4; ++ta)
          mx = fmaxf(mx, fmaxf(fmaxf(sacc[ta][q2][0], sacc[ta][q2][1]),
                               fmaxf(sacc[ta][q2][2], sacc[ta][q2][3])));
        mx = fmaxf(mx, __shfl_xor(mx, 16));
        mx = fmaxf(mx, __shfl_xor(mx, 32));
        bool rs = mx > mrun[q2] + 8.0f;
        resc |= rs;
        float mnew = rs ? mx : mrun[q2];
        corr[q2] = fexp2(mrun[q2] - mnew);
        mrun[q2] = mnew;
        float ls = 0.f;
#pragma unroll
        for (int ta = 0; ta < 4; ++ta)
#pragma unroll
          for (int r = 0; r < 4; ++r) {
            float e = fexp2(sacc[ta][q2][r] - mnew);
            sacc[ta][q2][r] = e;
            ls += e;
          }
        ls += __shfl_xor(ls, 16);
        ls += __shfl_xor(ls, 32);
        lrun[q2] = lrun[q2] * corr[q2] + ls;
      }

      if (__any(resc)) {
#pragma unroll
        for (int q2 = 0; q2 < 2; ++q2)
#pragma unroll
          for (int r = 0; r < 4; ++r) {
            float cD = __shfl(corr[q2], (lane & 48) | (((lane >> 4) << 2) + r));
#pragma unroll
            for (int fn = 0; fn < 8; ++fn) accO[q2][fn][r] *= cD;
          }
      }

#pragma unroll
      for (int q2 = 0; q2 < 2; ++q2) {
        int prow = w * 32 + q2 * 16 + c;
#pragma unroll
        for (int ta = 0; ta < 4; ++ta) {
          u16x4 pk;
          pk[0] = f2bf(sacc[ta][q2][0]); pk[1] = f2bf(sacc[ta][q2][1]);
          pk[2] = f2bf(sacc[ta][q2][2]); pk[3] = f2bf(sacc[ta][q2][3]);
          *(u16x4*)(&Plds[prow * 72 + ta * 16 + g * 4]) = pk;
        }
      }
    }

    if (havenext) asm volatile("s_waitcnt vmcnt(4)" ::: "memory");
    else          asm volatile("s_waitcnt vmcnt(0)" ::: "memory");
    __builtin_amdgcn_s_barrier();

    if (t0 <= qmaxw) {
      __builtin_amdgcn_s_setprio(1);
#pragma unroll
      for (int kk = 0; kk < 2; ++kk) {
        bf16x8 pa[2];
#pragma unroll
        for (int q2 = 0; q2 < 2; ++q2)
          pa[q2] = *(const bf16x8*)((const char*)Plds + (w * 32 + q2 * 16 + c) * 144 + (kk * 32 + g * 8) * 2);
#pragma unroll
        for (int fn = 0; fn < 8; ++fn) {
          int d = fn * 16 + c;
          int tt = kk * 32 + g * 8;
          bf16x8 vb = *(const bf16x8*)((const char*)Vlds + d * 128 + ((tt ^ ((d & 7) << 3)) << 1));
#pragma unroll
          for (int q2 = 0; q2 < 2; ++q2)
            accO[q2][fn] = mfma16(pa[q2], vb, accO[q2][fn]);
        }
      }
      __builtin_amdgcn_s_setprio(0);
    }
    __builtin_amdgcn_s_barrier();
  }

  const int b = head >> 4, nh = head & 15;
  float linv[2] = { 1.0f / lrun[0], 1.0f / lrun[1] };
#pragma unroll
  for (int q2 = 0; q2 < 2; ++q2)
#pragma unroll
    for (int r = 0; r < 4; ++r) {
      float inv = __shfl(linv[q2], (lane & 48) | (((lane >> 4) << 2) + r));
      int q = q0 + w * 32 + q2 * 16 + g * 4 + r;
      int m = q * 2 + b;
#pragma unroll
      for (int fn = 0; fn < 8; ++fn) {
        int h = nh * 128 + fn * 16 + c;
        ctx[(size_t)m * HID + h] = f2bf(accO[q2][fn][r] * inv);
      }
    }
}

extern "C" void kernel_launch(void* const* d_in, const int* in_sizes, int n_in,
                              void* d_out, int out_size, void* d_ws, size_t ws_size,
                              hipStream_t stream) {
  const float* hidden = (const float*)d_in[0];
  const float* Wqkv = (const float*)d_in[2];
  const float* bqkv = (const float*)d_in[3];
  const float* Wd   = (const float*)d_in[4];
  const float* bd   = (const float*)d_in[5];
  float* out = (float*)d_out;
  char* ws = (char*)d_ws;

  const size_t OFF_HID  = 0;
  const size_t OFF_WQKV = 16777216;
  const size_t OFF_WD   = 41943040;
  const size_t OFF_COS  = 50331648;
  const size_t OFF_SIN  = 50855936;
  const size_t OFF_Q    = 51380224;
  const size_t OFF_K    = 68157440;
  const size_t OFF_V    = 84934656;
  const size_t OFF_VT   = 101711872;
  if (ws_size < 118489088) return;

  unsigned short* hidb  = (unsigned short*)(ws + OFF_HID);
  unsigned short* wqkvb = (unsigned short*)(ws + OFF_WQKV);
  unsigned short* wdb   = (unsigned short*)(ws + OFF_WD);
  float* cosT = (float*)(ws + OFF_COS);
  float* sinT = (float*)(ws + OFF_SIN);
  unsigned short* Qsb = (unsigned short*)(ws + OFF_Q);
  unsigned short* Ksb = (unsigned short*)(ws + OFF_K);
  unsigned short* Vpb = (unsigned short*)(ws + OFF_V);
  unsigned short* Vtb = (unsigned short*)(ws + OFF_VT);
  unsigned short* ctxb = hidb;

  prep<<<25088, 256, 0, stream>>>(hidden, Wqkv, Wd, hidb, wqkvb, wdb, cosT, sinT);

  gemm_qkv<<<512, 512, 0, stream>>>(hidb, wqkvb, bqkv, Qsb, Ksb, Vpb, cosT, sinT);
  transpose_v<<<1024, 256, 0, stream>>>(Vpb, Vtb);
  attn<<<512, 256, 0, stream>>>(Qsb, Ksb, Vtb, ctxb);
  gemm_out<<<256, 512, 0, stream>>>(ctxb, wdb, bd, out);
}

// Round 9
// 250.792 us; speedup vs baseline: 1.4325x; 1.4325x over previous
//
#include <hip/hip_runtime.h>

#define SEQ   2048
#define BATCH 2
#define HID   2048
#define NHEAD 16
#define HDIM  128
#define MTOT  4096
#define KDIM  2048

typedef __attribute__((ext_vector_type(8))) short  bf16x8;
typedef __attribute__((ext_vector_type(4))) float  f32x4;
typedef __attribute__((ext_vector_type(4))) unsigned short u16x4;
typedef __attribute__((ext_vector_type(8))) unsigned short u16x8;

__device__ __forceinline__ unsigned short f2bf(float x) {
  unsigned u = __float_as_uint(x);
  u += 0x7fffu + ((u >> 16) & 1u);
  return (unsigned short)(u >> 16);
}

__device__ __forceinline__ float fexp2(float x) {
  float r;
  asm("v_exp_f32 %0, %1" : "=v"(r) : "v"(x));
  return r;
}

__device__ __forceinline__ void gl_lds16(const void* g, void* l) {
  __builtin_amdgcn_global_load_lds(
      (__attribute__((address_space(1))) void*)g,
      (__attribute__((address_space(3))) void*)l, 16, 0, 0);
}

__device__ __forceinline__ f32x4 mfma16(bf16x8 a, bf16x8 b, f32x4 c) {
  return __builtin_amdgcn_mfma_f32_16x16x32_bf16(a, b, c, 0, 0, 0);
}

// ---------------------------------------------------------------------------
// Fused prep (round-6 version): fp32->bf16 K-granule swizzle for ALL THREE
// matrices (k ^ (((r>>1)&3)<<3)) + RoPE cos/sin table.
// ---------------------------------------------------------------------------
__global__ __launch_bounds__(256, 8)
void prep(const float* __restrict__ hidden, const float* __restrict__ Wqkv,
          const float* __restrict__ Wd,
          unsigned short* __restrict__ hidb, unsigned short* __restrict__ wqkvb,
          unsigned short* __restrict__ wdb,
          float* __restrict__ cosT, float* __restrict__ sinT) {
  int bid = blockIdx.x;
  if (bid < 24576) {
    const float* src; unsigned short* dst; int lb;
    if (bid < 8192)       { src = hidden; dst = hidb;  lb = bid; }
    else if (bid < 20480) { src = Wqkv;   dst = wqkvb; lb = bid - 8192; }
    else                  { src = Wd;     dst = wdb;   lb = bid - 20480; }
    int i = lb * 256 + threadIdx.x;
    int base = i << 2;
    int r = base >> 11, k = base & 2047;
    f32x4 v = *(const f32x4*)(src + base);
    int kp = k ^ (((r >> 1) & 3) << 3);
    u16x4 o;
    o[0] = f2bf(v[0]); o[1] = f2bf(v[1]); o[2] = f2bf(v[2]); o[3] = f2bf(v[3]);
    *(u16x4*)(dst + (size_t)r * 2048 + kp) = o;
  } else {
    int idx = (bid - 24576) * 256 + threadIdx.x;   // 2048*64
    int s = idx >> 6, i = idx & 63;
    float inv = powf(1e-4f, (float)i * (1.0f / 64.0f));
    float a = (float)s * inv;
    cosT[idx] = cosf(a);
    sinT[idx] = sinf(a);
  }
}

// ---------------------------------------------------------------------------
// QKV GEMM (round-6 version, best measured: 107us, MfmaUtil 42%):
// 128x384 tile, BK=32, grid 512 = 2 full rounds, 8 waves = 2M x 4N,
// ring-3 LDS (96 KiB), SINGLE barrier per K-tile, vmcnt(4).
// ---------------------------------------------------------------------------
__global__ __launch_bounds__(512, 2)
void gemm_qkv(const unsigned short* __restrict__ A,
              const unsigned short* __restrict__ Bt,
              const float* __restrict__ bias,
              unsigned short* __restrict__ Qs,
              unsigned short* __restrict__ Ks,
              unsigned short* __restrict__ Vp,
              const float* __restrict__ cosT,
              const float* __restrict__ sinT)
{
  __shared__ alignas(16) char lds[98304];   // 96 KiB
  const int tid = threadIdx.x;
  const int wid = tid >> 6, lane = tid & 63, g = lane >> 4, c = lane & 15;
  const int wr = wid >> 2, wc = wid & 3;

  const int bid = blockIdx.x;
  const int swz = (bid & 7) * 64 + (bid >> 3);
  const int nblk = swz & 15, mblk = swz >> 4;
  const int m0 = mblk << 7;
  const int n0 = nblk * 384;
  const int nh = nblk;

  char* ldsb = (char*)lds;
  const int slotg = (g ^ ((c >> 1) & 3)) << 4;
  const char* ldsAr = ldsb + (wr * 64 + c) * 64 + slotg;
  const char* ldsBr = ldsb + 24576 + (wc * 16 + c) * 64 + slotg;

  const char* gA = (const char*)A  + (size_t)(m0 + (tid >> 2)) * 4096 + (tid & 3) * 16;
  const char* gB = (const char*)Bt + (size_t)(n0 + (tid >> 2)) * 4096 + (tid & 3) * 16;
  char* lA = ldsb + tid * 16;
  char* lB = ldsb + 24576 + tid * 16;

#define STG_A(T, BUF) gl_lds16(gA + (T) * 64, lA + (BUF) * 8192)
#define STG_B(T, BUF) do { const char* _g = gB + (T) * 64; char* _l = lB + (BUF) * 24576; \
    gl_lds16(_g, _l); gl_lds16(_g + 524288, _l + 8192); gl_lds16(_g + 1048576, _l + 16384); } while (0)

  f32x4 acc[4][6];
#pragma unroll
  for (int i = 0; i < 4; ++i)
#pragma unroll
    for (int j = 0; j < 6; ++j) {
      acc[i][j][0] = 0.f; acc[i][j][1] = 0.f; acc[i][j][2] = 0.f; acc[i][j][3] = 0.f;
    }

  bf16x8 a[4], b[6];
  const int NT = KDIM / 32;   // 64

#define TILE(T, BUF, BUFN) do {                                             \
    if ((T) + 2 < NT) { STG_A((T) + 2, BUFN); STG_B((T) + 2, BUFN); }       \
    _Pragma("unroll")                                                       \
    for (int mf = 0; mf < 4; ++mf)                                          \
      a[mf] = *(const bf16x8*)(ldsAr + (BUF) * 8192 + mf * 1024);           \
    _Pragma("unroll")                                                       \
    for (int nl = 0; nl < 6; ++nl)                                          \
      b[nl] = *(const bf16x8*)(ldsBr + (BUF) * 24576 + nl * 4096);          \
    __builtin_amdgcn_s_setprio(1);                                          \
    _Pragma("unroll")                                                       \
    for (int mf = 0; mf < 4; ++mf)                                          \
      _Pragma("unroll")                                                     \
      for (int nl = 0; nl < 6; ++nl)                                        \
        acc[mf][nl] = mfma16(a[mf], b[nl], acc[mf][nl]);                    \
    __builtin_amdgcn_s_setprio(0);                                          \
    if ((T) + 2 < NT) { asm volatile("s_waitcnt vmcnt(4)" ::: "memory"); }  \
    else              { asm volatile("s_waitcnt vmcnt(0)" ::: "memory"); }  \
    __builtin_amdgcn_s_barrier();                                           \
  } while (0)

  STG_A(0, 0); STG_B(0, 0);
  STG_A(1, 1); STG_B(1, 1);
  asm volatile("s_waitcnt vmcnt(4)" ::: "memory");
  __builtin_amdgcn_s_barrier();

  for (int t = 0; t < 63; t += 3) {
    TILE(t, 0, 2);
    TILE(t + 1, 1, 0);
    TILE(t + 2, 2, 1);
  }
  TILE(63, 0, 2);

  // ---- epilogue: bias + RoPE; nl pairs (0,1)=Q, (2,3)=K, (4,5)=V ----
  const float qsc = 0.08838834764831845f * 1.4426950408889634f; // 1/sqrt(128)*log2(e)
  const int dl = wc * 16 + c;   // 0..63
#pragma unroll
  for (int ar = 0; ar < 4; ++ar) {
#pragma unroll
    for (int rr = 0; rr < 4; ++rr) {
      int m = m0 + wr * 64 + ar * 16 + g * 4 + rr;
      int s = m >> 1, bb = m & 1;
      size_t plane = (size_t)(bb * NHEAD + nh) * (SEQ * HDIM);
      int swb = (s & 7) << 3;
      float co = cosT[s * 64 + dl], si = sinT[s * 64 + dl];
      {
        float xl = acc[ar][0][rr] + bias[n0 + dl];
        float xr = acc[ar][1][rr] + bias[n0 + 64 + dl];
        Qs[plane + (size_t)s * HDIM + (dl ^ swb)]        = f2bf((co * xl - si * xr) * qsc);
        Qs[plane + (size_t)s * HDIM + ((dl + 64) ^ swb)] = f2bf((si * xl + co * xr) * qsc);
      }
      {
        float xl = acc[ar][2][rr] + bias[n0 + 128 + dl];
        float xr = acc[ar][3][rr] + bias[n0 + 192 + dl];
        Ks[plane + (size_t)s * HDIM + (dl ^ swb)]        = f2bf(co * xl - si * xr);
        Ks[plane + (size_t)s * HDIM + ((dl + 64) ^ swb)] = f2bf(si * xl + co * xr);
      }
      Vp[plane + (size_t)s * HDIM + dl]      = f2bf(acc[ar][4][rr] + bias[n0 + 256 + dl]);
      Vp[plane + (size_t)s * HDIM + dl + 64] = f2bf(acc[ar][5][rr] + bias[n0 + 320 + dl]);
    }
  }
#undef TILE
#undef STG_A
#undef STG_B
}

// ---------------------------------------------------------------------------
// Dense projection GEMM (round-6 version): 128x256 tile, grid 256 = 1 round,
// ring-3, single barrier per K-tile, vmcnt(3).
// ---------------------------------------------------------------------------
__global__ __launch_bounds__(512, 2)
void gemm_out(const unsigned short* __restrict__ A,
              const unsigned short* __restrict__ Bt,
              const float* __restrict__ bias,
              float* __restrict__ Cout)
{
  __shared__ alignas(16) char lds[73728];   // 72 KiB
  const int tid = threadIdx.x;
  const int wid = tid >> 6, lane = tid & 63, g = lane >> 4, c = lane & 15;
  const int wr = wid >> 2, wc = wid & 3;

  const int bid = blockIdx.x;
  const int swz = (bid & 7) * 32 + (bid >> 3);
  const int nblk = swz >> 5, mblk = swz & 31;
  const int m0 = mblk << 7, n0 = nblk << 8;

  char* ldsb = (char*)lds;
  const int slotg = (g ^ ((c >> 1) & 3)) << 4;
  const char* ldsAr = ldsb + (wr * 64 + c) * 64 + slotg;
  const char* ldsBr = ldsb + 24576 + (wc * 64 + c) * 64 + slotg;

  const char* gA = (const char*)A  + (size_t)(m0 + (tid >> 2)) * 4096 + (tid & 3) * 16;
  const char* gB = (const char*)Bt + (size_t)(n0 + (tid >> 2)) * 4096 + (tid & 3) * 16;
  char* lA = ldsb + tid * 16;
  char* lB = ldsb + 24576 + tid * 16;

#define STG_A(T, BUF) gl_lds16(gA + (T) * 64, lA + (BUF) * 8192)
#define STG_B(T, BUF) do { const char* _g = gB + (T) * 64; char* _l = lB + (BUF) * 16384; \
    gl_lds16(_g, _l); gl_lds16(_g + 524288, _l + 8192); } while (0)

  f32x4 acc[4][4];
#pragma unroll
  for (int i = 0; i < 4; ++i)
#pragma unroll
    for (int j = 0; j < 4; ++j) {
      acc[i][j][0] = 0.f; acc[i][j][1] = 0.f; acc[i][j][2] = 0.f; acc[i][j][3] = 0.f;
    }

  bf16x8 a[4], b[4];
  const int NT = KDIM / 32;   // 64

#define TILE(T, BUF, BUFN) do {                                             \
    if ((T) + 2 < NT) { STG_A((T) + 2, BUFN); STG_B((T) + 2, BUFN); }       \
    _Pragma("unroll")                                                       \
    for (int mf = 0; mf < 4; ++mf)                                          \
      a[mf] = *(const bf16x8*)(ldsAr + (BUF) * 8192 + mf * 1024);           \
    _Pragma("unroll")                                                       \
    for (int nl = 0; nl < 4; ++nl)                                          \
      b[nl] = *(const bf16x8*)(ldsBr + (BUF) * 16384 + nl * 1024);          \
    __builtin_amdgcn_s_setprio(1);                                          \
    _Pragma("unroll")                                                       \
    for (int mf = 0; mf < 4; ++mf)                                          \
      _Pragma("unroll")                                                     \
      for (int nl = 0; nl < 4; ++nl)                                        \
        acc[mf][nl] = mfma16(a[mf], b[nl], acc[mf][nl]);                    \
    __builtin_amdgcn_s_setprio(0);                                          \
    if ((T) + 2 < NT) { asm volatile("s_waitcnt vmcnt(3)" ::: "memory"); }  \
    else              { asm volatile("s_waitcnt vmcnt(0)" ::: "memory"); }  \
    __builtin_amdgcn_s_barrier();                                           \
  } while (0)

  STG_A(0, 0); STG_B(0, 0);
  STG_A(1, 1); STG_B(1, 1);
  asm volatile("s_waitcnt vmcnt(3)" ::: "memory");
  __builtin_amdgcn_s_barrier();

  for (int t = 0; t < 63; t += 3) {
    TILE(t, 0, 2);
    TILE(t + 1, 1, 0);
    TILE(t + 2, 2, 1);
  }
  TILE(63, 0, 2);

#pragma unroll
  for (int mf = 0; mf < 4; ++mf)
#pragma unroll
    for (int rr = 0; rr < 4; ++rr) {
      int m = m0 + wr * 64 + mf * 16 + g * 4 + rr;
#pragma unroll
      for (int nl = 0; nl < 4; ++nl) {
        int n = n0 + wc * 64 + nl * 16 + c;
        Cout[(size_t)m * HID + n] = acc[mf][nl][rr] + bias[n];
      }
    }
#undef TILE
#undef STG_A
#undef STG_B
}

// V [plane][t][d] -> Vt [plane][d][t], t-granule swizzled: (t ^ ((d&7)<<3))
__global__ __launch_bounds__(256, 4)
void transpose_v(const unsigned short* __restrict__ Vp, unsigned short* __restrict__ Vt) {
  __shared__ alignas(16) unsigned short T[64 * 136];
  const int plane = blockIdx.x >> 5;
  const int t0 = (blockIdx.x & 31) << 6;
  const size_t pbase = (size_t)plane * (SEQ * HDIM);
  const int tid = threadIdx.x;
  {
    int t = tid >> 2, d0 = (tid & 3) << 5;
    const unsigned short* src = Vp + pbase + (size_t)(t0 + t) * HDIM + d0;
#pragma unroll
    for (int j = 0; j < 4; ++j) {
      u16x8 v = *(const u16x8*)(src + j * 8);
      *(u16x8*)(&T[t * 136 + d0 + j * 8]) = v;
    }
  }
  __syncthreads();
  {
    int d = tid >> 1, half = tid & 1;
    unsigned short* dstp = Vt + pbase + (size_t)d * SEQ;
    int swb = (d & 7) << 3;
#pragma unroll
    for (int gg = 0; gg < 4; ++gg) {
      u16x8 v;
#pragma unroll
      for (int e = 0; e < 8; ++e)
        v[e] = T[(half * 32 + gg * 8 + e) * 136 + d];
      int tloc = half * 32 + gg * 8;
      *(u16x8*)(dstp + ((t0 + tloc) ^ swb)) = v;
    }
  }
}

// ---------------------------------------------------------------------------
// Flash attention, CAUSAL PAIR SCHEDULING: 256 blocks x 512 threads.
// Block (head, j): waves 0-3 own q-block qb=15-j, waves 4-7 own qb=j,
// SHARING one K/V staging stream (tiles 0..2*(15-j)+1). Uniform 36
// compute-tile-halves per block; K/V of a head stays on one XCD
// (bid%8 == head%8). Staging tiles 8704 -> 6400 (-26%), barriers -26%.
// LDS: K dbuf 32K + V 16K + P 36K = 84 KiB -> 1 block/CU, 8 waves.
// Per-thread stage = 2 K ops + 2 V ops -> vmcnt(4)/(2)/(0), never a
// mid-loop full drain.
// ---------------------------------------------------------------------------
__global__ __launch_bounds__(512, 2)
void attn(const unsigned short* __restrict__ Qs,
          const unsigned short* __restrict__ Ks,
          const unsigned short* __restrict__ Vt,
          unsigned short* __restrict__ ctx)
{
  __shared__ alignas(16) unsigned short Klds[2][64 * 128];   // 2 x 16 KiB
  __shared__ alignas(16) unsigned short Vlds[128 * 64];      // 16 KiB
  __shared__ alignas(16) unsigned short Plds[256 * 72];      // 36 KiB
  const int tid = threadIdx.x;
  const int w = tid >> 6, lane = tid & 63, g = lane >> 4, c = lane & 15;
  const int bid = blockIdx.x;
  const int head = bid & 31;
  const int j = bid >> 5;                 // 0..7
  const int qbh = 15 - j;
  const int q0w = (w < 4) ? ((qbh << 7) + w * 32) : ((j << 7) + (w - 4) * 32);
  const size_t plane = (size_t)head * (SEQ * HDIM);
  const unsigned short* Qp = Qs + plane;

  // Q fragments (B-operand: col = c -> q-row)
  bf16x8 qf[2][4];
#pragma unroll
  for (int q2 = 0; q2 < 2; ++q2) {
    int s = q0w + q2 * 16 + c;
    int swb = (s & 7) << 3;
#pragma unroll
    for (int kk = 0; kk < 4; ++kk) {
      int d0 = kk * 32 + g * 8;
      qf[q2][kk] = *(const bf16x8*)(Qp + (size_t)s * HDIM + (d0 ^ swb));
    }
  }

  f32x4 accO[2][8];
#pragma unroll
  for (int i = 0; i < 2; ++i)
#pragma unroll
    for (int jj = 0; jj < 8; ++jj) {
      accO[i][jj][0] = 0.f; accO[i][jj][1] = 0.f; accO[i][jj][2] = 0.f; accO[i][jj][3] = 0.f;
    }
  float mrun[2] = { -1e30f, -1e30f };
  float lrun[2] = { 0.f, 0.f };

  const char* Kg = (const char*)(Ks + plane) + (tid >> 4) * 256 + (tid & 15) * 16;
  const char* Vg = (const char*)(Vt + plane) + (size_t)(tid >> 3) * 4096 + (tid & 7) * 16;

  const int ntiles = (qbh << 1) + 2;
  const int qminw = q0w;
  const int qmaxw = q0w + 31;

  // Prologue: stage K(0) into buf 0 (rows tid>>4 and +32)
  gl_lds16(Kg,        (char*)Klds[0] + tid * 16);
  gl_lds16(Kg + 8192, (char*)Klds[0] + tid * 16 + 8192);

  for (int kt = 0; kt < ntiles; ++kt) {
    const int t0 = kt << 6;
    const bool havenext = (kt + 1 < ntiles);

    // Issue V(kt) then K(kt+1)  (2 ops each per thread)
    gl_lds16(Vg + t0 * 2,          (char*)Vlds + tid * 16);
    gl_lds16(Vg + t0 * 2 + 262144, (char*)Vlds + tid * 16 + 8192);
    if (havenext) {
      char* kd = (char*)Klds[(kt + 1) & 1] + tid * 16;
      gl_lds16(Kg + (size_t)(t0 + 64) * 256,        kd);
      gl_lds16(Kg + (size_t)(t0 + 64) * 256 + 8192, kd + 8192);
    }
    // K(kt) landed; V(kt)+K(kt+1) stay in flight
    if (havenext) asm volatile("s_waitcnt vmcnt(4)" ::: "memory");
    else          asm volatile("s_waitcnt vmcnt(2)" ::: "memory");
    __builtin_amdgcn_s_barrier();

    if (t0 <= qmaxw) {
      const char* Kb = (const char*)Klds[kt & 1];
      f32x4 sacc[4][2];
#pragma unroll
      for (int i = 0; i < 4; ++i)
#pragma unroll
        for (int jj = 0; jj < 2; ++jj) {
          sacc[i][jj][0] = 0.f; sacc[i][jj][1] = 0.f; sacc[i][jj][2] = 0.f; sacc[i][jj][3] = 0.f;
        }
      __builtin_amdgcn_s_setprio(1);
#pragma unroll
      for (int kk = 0; kk < 4; ++kk) {
        bf16x8 kf[4];
#pragma unroll
        for (int ta = 0; ta < 4; ++ta) {
          int t = ta * 16 + c;
          int d0 = kk * 32 + g * 8;
          kf[ta] = *(const bf16x8*)(Kb + t * 256 + ((d0 ^ ((t & 7) << 3)) << 1));
        }
#pragma unroll
        for (int ta = 0; ta < 4; ++ta)
#pragma unroll
          for (int q2 = 0; q2 < 2; ++q2)
            sacc[ta][q2] = mfma16(kf[ta], qf[q2][kk], sacc[ta][q2]);
      }
      __builtin_amdgcn_s_setprio(0);

      // causal mask: D[row=g*4+r -> t][col=c -> q]
      if (t0 + 63 > qminw) {
#pragma unroll
        for (int ta = 0; ta < 4; ++ta)
#pragma unroll
          for (int q2 = 0; q2 < 2; ++q2)
#pragma unroll
            for (int r = 0; r < 4; ++r) {
              int t = t0 + ta * 16 + g * 4 + r;
              int q = qminw + q2 * 16 + c;
              if (t > q) sacc[ta][q2][r] = -30000.f;
            }
      }

      float corr[2];
      bool resc = false;
#pragma unroll
      for (int q2 = 0; q2 < 2; ++q2) {
        float mx = -30000.f;
#pragma unroll
        for (int ta = 0; ta < 4; ++ta)
          mx = fmaxf(mx, fmaxf(fmaxf(sacc[ta][q2][0], sacc[ta][q2][1]),
                               fmaxf(sacc[ta][q2][2], sacc[ta][q2][3])));
        mx = fmaxf(mx, __shfl_xor(mx, 16));
        mx = fmaxf(mx, __shfl_xor(mx, 32));
        bool rs = mx > mrun[q2] + 8.0f;   // T13 defer-max
        resc |= rs;
        float mnew = rs ? mx : mrun[q2];
        corr[q2] = fexp2(mrun[q2] - mnew);
        mrun[q2] = mnew;
        float ls = 0.f;
#pragma unroll
        for (int ta = 0; ta < 4; ++ta)
#pragma unroll
          for (int r = 0; r < 4; ++r) {
            float e = fexp2(sacc[ta][q2][r] - mnew);
            sacc[ta][q2][r] = e;
            ls += e;
          }
        ls += __shfl_xor(ls, 16);
        ls += __shfl_xor(ls, 32);
        lrun[q2] = lrun[q2] * corr[q2] + ls;
      }

      if (__any(resc)) {
#pragma unroll
        for (int q2 = 0; q2 < 2; ++q2)
#pragma unroll
          for (int r = 0; r < 4; ++r) {
            float cD = __shfl(corr[q2], (lane & 48) | (((lane >> 4) << 2) + r));
#pragma unroll
            for (int fn = 0; fn < 8; ++fn) accO[q2][fn][r] *= cD;
          }
      }

#pragma unroll
      for (int q2 = 0; q2 < 2; ++q2) {
        int prow = w * 32 + q2 * 16 + c;
#pragma unroll
        for (int ta = 0; ta < 4; ++ta) {
          u16x4 pk;
          pk[0] = f2bf(sacc[ta][q2][0]); pk[1] = f2bf(sacc[ta][q2][1]);
          pk[2] = f2bf(sacc[ta][q2][2]); pk[3] = f2bf(sacc[ta][q2][3]);
          *(u16x4*)(&Plds[prow * 72 + ta * 16 + g * 4]) = pk;
        }
      }
    }

    // V(kt) landed (K(kt+1) may still fly)
    if (havenext) asm volatile("s_waitcnt vmcnt(2)" ::: "memory");
    else          asm volatile("s_waitcnt vmcnt(0)" ::: "memory");
    __builtin_amdgcn_s_barrier();

    if (t0 <= qmaxw) {
      __builtin_amdgcn_s_setprio(1);
#pragma unroll
      for (int kk = 0; kk < 2; ++kk) {
        bf16x8 pa[2];
#pragma unroll
        for (int q2 = 0; q2 < 2; ++q2)
          pa[q2] = *(const bf16x8*)((const char*)Plds + (w * 32 + q2 * 16 + c) * 144 + (kk * 32 + g * 8) * 2);
#pragma unroll
        for (int fn = 0; fn < 8; ++fn) {
          int d = fn * 16 + c;
          int tt = kk * 32 + g * 8;
          bf16x8 vb = *(const bf16x8*)((const char*)Vlds + d * 128 + ((tt ^ ((d & 7) << 3)) << 1));
#pragma unroll
          for (int q2 = 0; q2 < 2; ++q2)
            accO[q2][fn] = mfma16(pa[q2], vb, accO[q2][fn]);
        }
      }
      __builtin_amdgcn_s_setprio(0);
    }
    __builtin_amdgcn_s_barrier();   // LDS reads done before next stage
  }

  const int b = head >> 4, nh = head & 15;
  float linv[2] = { 1.0f / lrun[0], 1.0f / lrun[1] };
#pragma unroll
  for (int q2 = 0; q2 < 2; ++q2)
#pragma unroll
    for (int r = 0; r < 4; ++r) {
      float inv = __shfl(linv[q2], (lane & 48) | (((lane >> 4) << 2) + r));
      int q = q0w + q2 * 16 + g * 4 + r;
      int m = q * 2 + b;
      int swb = ((m >> 1) & 3) << 3;
#pragma unroll
      for (int fn = 0; fn < 8; ++fn) {
        int h = nh * 128 + fn * 16 + c;
        ctx[(size_t)m * HID + (h ^ swb)] = f2bf(accO[q2][fn][r] * inv);
      }
    }
}

extern "C" void kernel_launch(void* const* d_in, const int* in_sizes, int n_in,
                              void* d_out, int out_size, void* d_ws, size_t ws_size,
                              hipStream_t stream) {
  const float* hidden = (const float*)d_in[0];
  const float* Wqkv = (const float*)d_in[2];
  const float* bqkv = (const float*)d_in[3];
  const float* Wd   = (const float*)d_in[4];
  const float* bd   = (const float*)d_in[5];
  float* out = (float*)d_out;
  char* ws = (char*)d_ws;

  const size_t OFF_HID  = 0;
  const size_t OFF_WQKV = 16777216;
  const size_t OFF_WD   = 41943040;
  const size_t OFF_COS  = 50331648;
  const size_t OFF_SIN  = 50855936;
  const size_t OFF_Q    = 51380224;
  const size_t OFF_K    = 68157440;
  const size_t OFF_V    = 84934656;
  const size_t OFF_VT   = 101711872;
  if (ws_size < 118489088) return;

  unsigned short* hidb  = (unsigned short*)(ws + OFF_HID);
  unsigned short* wqkvb = (unsigned short*)(ws + OFF_WQKV);
  unsigned short* wdb   = (unsigned short*)(ws + OFF_WD);
  float* cosT = (float*)(ws + OFF_COS);
  float* sinT = (float*)(ws + OFF_SIN);
  unsigned short* Qsb = (unsigned short*)(ws + OFF_Q);
  unsigned short* Ksb = (unsigned short*)(ws + OFF_K);
  unsigned short* Vpb = (unsigned short*)(ws + OFF_V);
  unsigned short* Vtb = (unsigned short*)(ws + OFF_VT);
  unsigned short* ctxb = hidb;

  prep<<<25088, 256, 0, stream>>>(hidden, Wqkv, Wd, hidb, wqkvb, wdb, cosT, sinT);

  gemm_qkv<<<512, 512, 0, stream>>>(hidb, wqkvb, bqkv, Qsb, Ksb, Vpb, cosT, sinT);
  transpose_v<<<1024, 256, 0, stream>>>(Vpb, Vtb);
  attn<<<256, 512, 0, stream>>>(Qsb, Ksb, Vtb, ctxb);
  gemm_out<<<256, 512, 0, stream>>>(ctxb, wdb, bd, out);
}

// Round 10
// 242.640 us; speedup vs baseline: 1.4806x; 1.0336x over previous
//
#include <hip/hip_runtime.h>

#define SEQ   2048
#define BATCH 2
#define HID   2048
#define NHEAD 16
#define HDIM  128
#define MTOT  4096
#define KDIM  2048

typedef __attribute__((ext_vector_type(8))) short  bf16x8;
typedef __attribute__((ext_vector_type(4))) float  f32x4;
typedef __attribute__((ext_vector_type(4))) unsigned short u16x4;
typedef __attribute__((ext_vector_type(8))) unsigned short u16x8;

__device__ __forceinline__ unsigned short f2bf(float x) {
  unsigned u = __float_as_uint(x);
  u += 0x7fffu + ((u >> 16) & 1u);
  return (unsigned short)(u >> 16);
}

__device__ __forceinline__ float fexp2(float x) {
  float r;
  asm("v_exp_f32 %0, %1" : "=v"(r) : "v"(x));
  return r;
}

__device__ __forceinline__ void gl_lds16(const void* g, void* l) {
  __builtin_amdgcn_global_load_lds(
      (__attribute__((address_space(1))) void*)g,
      (__attribute__((address_space(3))) void*)l, 16, 0, 0);
}

__device__ __forceinline__ f32x4 mfma16(bf16x8 a, bf16x8 b, f32x4 c) {
  return __builtin_amdgcn_mfma_f32_16x16x32_bf16(a, b, c, 0, 0, 0);
}

// ---------------------------------------------------------------------------
// Fused prep: fp32->bf16 K-granule swizzle (k ^ (((r>>1)&3)<<3)) for all
// three matrices + RoPE cos/sin table.
// ---------------------------------------------------------------------------
__global__ __launch_bounds__(256, 8)
void prep(const float* __restrict__ hidden, const float* __restrict__ Wqkv,
          const float* __restrict__ Wd,
          unsigned short* __restrict__ hidb, unsigned short* __restrict__ wqkvb,
          unsigned short* __restrict__ wdb,
          float* __restrict__ cosT, float* __restrict__ sinT) {
  int bid = blockIdx.x;
  if (bid < 24576) {
    const float* src; unsigned short* dst; int lb;
    if (bid < 8192)       { src = hidden; dst = hidb;  lb = bid; }
    else if (bid < 20480) { src = Wqkv;   dst = wqkvb; lb = bid - 8192; }
    else                  { src = Wd;     dst = wdb;   lb = bid - 20480; }
    int i = lb * 256 + threadIdx.x;
    int base = i << 2;
    int r = base >> 11, k = base & 2047;
    f32x4 v = *(const f32x4*)(src + base);
    int kp = k ^ (((r >> 1) & 3) << 3);
    u16x4 o;
    o[0] = f2bf(v[0]); o[1] = f2bf(v[1]); o[2] = f2bf(v[2]); o[3] = f2bf(v[3]);
    *(u16x4*)(dst + (size_t)r * 2048 + kp) = o;
  } else {
    int idx = (bid - 24576) * 256 + threadIdx.x;   // 2048*64
    int s = idx >> 6, i = idx & 63;
    float inv = powf(1e-4f, (float)i * (1.0f / 64.0f));
    float a = (float)s * inv;
    cosT[idx] = cosf(a);
    sinT[idx] = sinf(a);
  }
}

// ---------------------------------------------------------------------------
// QKV GEMM (round-6 core, best measured 107us) + FUSED V-TRANSPOSE EPILOGUE.
// 128x384 tile, BK=32, grid 512 = 2 full rounds, 8 waves = 2M x 4N,
// ring-3 LDS (96 KiB), single barrier per K-tile, vmcnt(4).
// Epilogue: Q/K -> RoPE'd swizzled [b,nh,s,d] as before; V -> bias, staged
// through LDS [2][64][136] and written TRANSPOSED+t-swizzled directly into
// Vt[plane][d][t] (replaces the separate transpose_v kernel: block's s-range
// (64 per batch) x d(128) is exactly one transpose tile).
// ---------------------------------------------------------------------------
__global__ __launch_bounds__(512, 2)
void gemm_qkv(const unsigned short* __restrict__ A,
              const unsigned short* __restrict__ Bt,
              const float* __restrict__ bias,
              unsigned short* __restrict__ Qs,
              unsigned short* __restrict__ Ks,
              unsigned short* __restrict__ Vt,
              const float* __restrict__ cosT,
              const float* __restrict__ sinT)
{
  __shared__ alignas(16) char lds[98304];   // 96 KiB
  const int tid = threadIdx.x;
  const int wid = tid >> 6, lane = tid & 63, g = lane >> 4, c = lane & 15;
  const int wr = wid >> 2, wc = wid & 3;

  const int bid = blockIdx.x;
  const int swz = (bid & 7) * 64 + (bid >> 3);
  const int nblk = swz & 15, mblk = swz >> 4;
  const int m0 = mblk << 7;
  const int n0 = nblk * 384;
  const int nh = nblk;

  char* ldsb = (char*)lds;
  const int slotg = (g ^ ((c >> 1) & 3)) << 4;
  const char* ldsAr = ldsb + (wr * 64 + c) * 64 + slotg;
  const char* ldsBr = ldsb + 24576 + (wc * 16 + c) * 64 + slotg;

  const char* gA = (const char*)A  + (size_t)(m0 + (tid >> 2)) * 4096 + (tid & 3) * 16;
  const char* gB = (const char*)Bt + (size_t)(n0 + (tid >> 2)) * 4096 + (tid & 3) * 16;
  char* lA = ldsb + tid * 16;
  char* lB = ldsb + 24576 + tid * 16;

#define STG_A(T, BUF) gl_lds16(gA + (T) * 64, lA + (BUF) * 8192)
#define STG_B(T, BUF) do { const char* _g = gB + (T) * 64; char* _l = lB + (BUF) * 24576; \
    gl_lds16(_g, _l); gl_lds16(_g + 524288, _l + 8192); gl_lds16(_g + 1048576, _l + 16384); } while (0)

  f32x4 acc[4][6];
#pragma unroll
  for (int i = 0; i < 4; ++i)
#pragma unroll
    for (int j = 0; j < 6; ++j) {
      acc[i][j][0] = 0.f; acc[i][j][1] = 0.f; acc[i][j][2] = 0.f; acc[i][j][3] = 0.f;
    }

  bf16x8 a[4], b[6];
  const int NT = KDIM / 32;   // 64

#define TILE(T, BUF, BUFN) do {                                             \
    if ((T) + 2 < NT) { STG_A((T) + 2, BUFN); STG_B((T) + 2, BUFN); }       \
    _Pragma("unroll")                                                       \
    for (int mf = 0; mf < 4; ++mf)                                          \
      a[mf] = *(const bf16x8*)(ldsAr + (BUF) * 8192 + mf * 1024);           \
    _Pragma("unroll")                                                       \
    for (int nl = 0; nl < 6; ++nl)                                          \
      b[nl] = *(const bf16x8*)(ldsBr + (BUF) * 24576 + nl * 4096);          \
    __builtin_amdgcn_s_setprio(1);                                          \
    _Pragma("unroll")                                                       \
    for (int mf = 0; mf < 4; ++mf)                                          \
      _Pragma("unroll")                                                     \
      for (int nl = 0; nl < 6; ++nl)                                        \
        acc[mf][nl] = mfma16(a[mf], b[nl], acc[mf][nl]);                    \
    __builtin_amdgcn_s_setprio(0);                                          \
    if ((T) + 2 < NT) { asm volatile("s_waitcnt vmcnt(4)" ::: "memory"); }  \
    else              { asm volatile("s_waitcnt vmcnt(0)" ::: "memory"); }  \
    __builtin_amdgcn_s_barrier();                                           \
  } while (0)

  STG_A(0, 0); STG_B(0, 0);
  STG_A(1, 1); STG_B(1, 1);
  asm volatile("s_waitcnt vmcnt(4)" ::: "memory");
  __builtin_amdgcn_s_barrier();

  for (int t = 0; t < 63; t += 3) {
    TILE(t, 0, 2);
    TILE(t + 1, 1, 0);
    TILE(t + 2, 2, 1);
  }
  TILE(63, 0, 2);

  // ---- epilogue ----
  // nl pairs: (0,1)=Q, (2,3)=K (RoPE + swizzled store), (4,5)=V (bias -> LDS)
  const float qsc = 0.08838834764831845f * 1.4426950408889634f; // 1/sqrt(128)*log2(e)
  const int dl = wc * 16 + c;   // 0..63
  unsigned short* Vtmp = (unsigned short*)ldsb;   // [2][64][136] = 34 KiB
  const int s0 = m0 >> 1;
#pragma unroll
  for (int ar = 0; ar < 4; ++ar) {
#pragma unroll
    for (int rr = 0; rr < 4; ++rr) {
      int m = m0 + wr * 64 + ar * 16 + g * 4 + rr;
      int s = m >> 1, bb = m & 1;   // bb == rr&1
      size_t plane = (size_t)(bb * NHEAD + nh) * (SEQ * HDIM);
      int swb = (s & 7) << 3;
      float co = cosT[s * 64 + dl], si = sinT[s * 64 + dl];
      {
        float xl = acc[ar][0][rr] + bias[n0 + dl];
        float xr = acc[ar][1][rr] + bias[n0 + 64 + dl];
        Qs[plane + (size_t)s * HDIM + (dl ^ swb)]        = f2bf((co * xl - si * xr) * qsc);
        Qs[plane + (size_t)s * HDIM + ((dl + 64) ^ swb)] = f2bf((si * xl + co * xr) * qsc);
      }
      {
        float xl = acc[ar][2][rr] + bias[n0 + 128 + dl];
        float xr = acc[ar][3][rr] + bias[n0 + 192 + dl];
        Ks[plane + (size_t)s * HDIM + (dl ^ swb)]        = f2bf(co * xl - si * xr);
        Ks[plane + (size_t)s * HDIM + ((dl + 64) ^ swb)] = f2bf(si * xl + co * xr);
      }
      {
        int sloc = s - s0;                         // wr*32 + ar*8 + g*2 + (rr>>1)
        Vtmp[(bb * 64 + sloc) * 136 + dl]      = f2bf(acc[ar][4][rr] + bias[n0 + 256 + dl]);
        Vtmp[(bb * 64 + sloc) * 136 + dl + 64] = f2bf(acc[ar][5][rr] + bias[n0 + 320 + dl]);
      }
    }
  }
  __syncthreads();
  // transposed coalesced write: Vt[plane][d][t], t-swizzled (t ^ ((d&7)<<3))
  {
    int b2 = tid >> 8, r = tid & 255;
    int d = r >> 1, half = r & 1;
    size_t planeV = (size_t)(b2 * NHEAD + nh) * (SEQ * HDIM);
    unsigned short* dstp = Vt + planeV + (size_t)d * SEQ + s0;
    int swb = (d & 7) << 3;
#pragma unroll
    for (int gg = 0; gg < 4; ++gg) {
      u16x8 v;
#pragma unroll
      for (int e = 0; e < 8; ++e)
        v[e] = Vtmp[(b2 * 64 + half * 32 + gg * 8 + e) * 136 + d];
      int tloc = half * 32 + gg * 8;
      *(u16x8*)(dstp + (tloc ^ swb)) = v;   // s0 is 64-aligned, swb<64
    }
  }
#undef TILE
#undef STG_A
#undef STG_B
}

// ---------------------------------------------------------------------------
// Dense projection GEMM (round-6 version): 128x256 tile, grid 256 = 1 round,
// ring-3, single barrier per K-tile, vmcnt(3).
// ---------------------------------------------------------------------------
__global__ __launch_bounds__(512, 2)
void gemm_out(const unsigned short* __restrict__ A,
              const unsigned short* __restrict__ Bt,
              const float* __restrict__ bias,
              float* __restrict__ Cout)
{
  __shared__ alignas(16) char lds[73728];   // 72 KiB
  const int tid = threadIdx.x;
  const int wid = tid >> 6, lane = tid & 63, g = lane >> 4, c = lane & 15;
  const int wr = wid >> 2, wc = wid & 3;

  const int bid = blockIdx.x;
  const int swz = (bid & 7) * 32 + (bid >> 3);
  const int nblk = swz >> 5, mblk = swz & 31;
  const int m0 = mblk << 7, n0 = nblk << 8;

  char* ldsb = (char*)lds;
  const int slotg = (g ^ ((c >> 1) & 3)) << 4;
  const char* ldsAr = ldsb + (wr * 64 + c) * 64 + slotg;
  const char* ldsBr = ldsb + 24576 + (wc * 64 + c) * 64 + slotg;

  const char* gA = (const char*)A  + (size_t)(m0 + (tid >> 2)) * 4096 + (tid & 3) * 16;
  const char* gB = (const char*)Bt + (size_t)(n0 + (tid >> 2)) * 4096 + (tid & 3) * 16;
  char* lA = ldsb + tid * 16;
  char* lB = ldsb + 24576 + tid * 16;

#define STG_A(T, BUF) gl_lds16(gA + (T) * 64, lA + (BUF) * 8192)
#define STG_B(T, BUF) do { const char* _g = gB + (T) * 64; char* _l = lB + (BUF) * 16384; \
    gl_lds16(_g, _l); gl_lds16(_g + 524288, _l + 8192); } while (0)

  f32x4 acc[4][4];
#pragma unroll
  for (int i = 0; i < 4; ++i)
#pragma unroll
    for (int j = 0; j < 4; ++j) {
      acc[i][j][0] = 0.f; acc[i][j][1] = 0.f; acc[i][j][2] = 0.f; acc[i][j][3] = 0.f;
    }

  bf16x8 a[4], b[4];
  const int NT = KDIM / 32;   // 64

#define TILE(T, BUF, BUFN) do {                                             \
    if ((T) + 2 < NT) { STG_A((T) + 2, BUFN); STG_B((T) + 2, BUFN); }       \
    _Pragma("unroll")                                                       \
    for (int mf = 0; mf < 4; ++mf)                                          \
      a[mf] = *(const bf16x8*)(ldsAr + (BUF) * 8192 + mf * 1024);           \
    _Pragma("unroll")                                                       \
    for (int nl = 0; nl < 4; ++nl)                                          \
      b[nl] = *(const bf16x8*)(ldsBr + (BUF) * 16384 + nl * 1024);          \
    __builtin_amdgcn_s_setprio(1);                                          \
    _Pragma("unroll")                                                       \
    for (int mf = 0; mf < 4; ++mf)                                          \
      _Pragma("unroll")                                                     \
      for (int nl = 0; nl < 4; ++nl)                                        \
        acc[mf][nl] = mfma16(a[mf], b[nl], acc[mf][nl]);                    \
    __builtin_amdgcn_s_setprio(0);                                          \
    if ((T) + 2 < NT) { asm volatile("s_waitcnt vmcnt(3)" ::: "memory"); }  \
    else              { asm volatile("s_waitcnt vmcnt(0)" ::: "memory"); }  \
    __builtin_amdgcn_s_barrier();                                           \
  } while (0)

  STG_A(0, 0); STG_B(0, 0);
  STG_A(1, 1); STG_B(1, 1);
  asm volatile("s_waitcnt vmcnt(3)" ::: "memory");
  __builtin_amdgcn_s_barrier();

  for (int t = 0; t < 63; t += 3) {
    TILE(t, 0, 2);
    TILE(t + 1, 1, 0);
    TILE(t + 2, 2, 1);
  }
  TILE(63, 0, 2);

#pragma unroll
  for (int mf = 0; mf < 4; ++mf)
#pragma unroll
    for (int rr = 0; rr < 4; ++rr) {
      int m = m0 + wr * 64 + mf * 16 + g * 4 + rr;
#pragma unroll
      for (int nl = 0; nl < 4; ++nl) {
        int n = n0 + wc * 64 + nl * 16 + c;
        Cout[(size_t)m * HID + n] = acc[mf][nl][rr] + bias[n];
      }
    }
#undef TILE
#undef STG_A
#undef STG_B
}

// ---------------------------------------------------------------------------
// Flash attention (round-9 pair-scheduled version, unchanged)
// ---------------------------------------------------------------------------
__global__ __launch_bounds__(512, 2)
void attn(const unsigned short* __restrict__ Qs,
          const unsigned short* __restrict__ Ks,
          const unsigned short* __restrict__ Vt,
          unsigned short* __restrict__ ctx)
{
  __shared__ alignas(16) unsigned short Klds[2][64 * 128];   // 2 x 16 KiB
  __shared__ alignas(16) unsigned short Vlds[128 * 64];      // 16 KiB
  __shared__ alignas(16) unsigned short Plds[256 * 72];      // 36 KiB
  const int tid = threadIdx.x;
  const int w = tid >> 6, lane = tid & 63, g = lane >> 4, c = lane & 15;
  const int bid = blockIdx.x;
  const int head = bid & 31;
  const int j = bid >> 5;                 // 0..7
  const int qbh = 15 - j;
  const int q0w = (w < 4) ? ((qbh << 7) + w * 32) : ((j << 7) + (w - 4) * 32);
  const size_t plane = (size_t)head * (SEQ * HDIM);
  const unsigned short* Qp = Qs + plane;

  bf16x8 qf[2][4];
#pragma unroll
  for (int q2 = 0; q2 < 2; ++q2) {
    int s = q0w + q2 * 16 + c;
    int swb = (s & 7) << 3;
#pragma unroll
    for (int kk = 0; kk < 4; ++kk) {
      int d0 = kk * 32 + g * 8;
      qf[q2][kk] = *(const bf16x8*)(Qp + (size_t)s * HDIM + (d0 ^ swb));
    }
  }

  f32x4 accO[2][8];
#pragma unroll
  for (int i = 0; i < 2; ++i)
#pragma unroll
    for (int jj = 0; jj < 8; ++jj) {
      accO[i][jj][0] = 0.f; accO[i][jj][1] = 0.f; accO[i][jj][2] = 0.f; accO[i][jj][3] = 0.f;
    }
  float mrun[2] = { -1e30f, -1e30f };
  float lrun[2] = { 0.f, 0.f };

  const char* Kg = (const char*)(Ks + plane) + (tid >> 4) * 256 + (tid & 15) * 16;
  const char* Vg = (const char*)(Vt + plane) + (size_t)(tid >> 3) * 4096 + (tid & 7) * 16;

  const int ntiles = (qbh << 1) + 2;
  const int qminw = q0w;
  const int qmaxw = q0w + 31;

  gl_lds16(Kg,        (char*)Klds[0] + tid * 16);
  gl_lds16(Kg + 8192, (char*)Klds[0] + tid * 16 + 8192);

  for (int kt = 0; kt < ntiles; ++kt) {
    const int t0 = kt << 6;
    const bool havenext = (kt + 1 < ntiles);

    gl_lds16(Vg + t0 * 2,          (char*)Vlds + tid * 16);
    gl_lds16(Vg + t0 * 2 + 262144, (char*)Vlds + tid * 16 + 8192);
    if (havenext) {
      char* kd = (char*)Klds[(kt + 1) & 1] + tid * 16;
      gl_lds16(Kg + (size_t)(t0 + 64) * 256,        kd);
      gl_lds16(Kg + (size_t)(t0 + 64) * 256 + 8192, kd + 8192);
    }
    if (havenext) asm volatile("s_waitcnt vmcnt(4)" ::: "memory");
    else          asm volatile("s_waitcnt vmcnt(2)" ::: "memory");
    __builtin_amdgcn_s_barrier();

    if (t0 <= qmaxw) {
      const char* Kb = (const char*)Klds[kt & 1];
      f32x4 sacc[4][2];
#pragma unroll
      for (int i = 0; i < 4; ++i)
#pragma unroll
        for (int jj = 0; jj < 2; ++jj) {
          sacc[i][jj][0] = 0.f; sacc[i][jj][1] = 0.f; sacc[i][jj][2] = 0.f; sacc[i][jj][3] = 0.f;
        }
      __builtin_amdgcn_s_setprio(1);
#pragma unroll
      for (int kk = 0; kk < 4; ++kk) {
        bf16x8 kf[4];
#pragma unroll
        for (int ta = 0; ta < 4; ++ta) {
          int t = ta * 16 + c;
          int d0 = kk * 32 + g * 8;
          kf[ta] = *(const bf16x8*)(Kb + t * 256 + ((d0 ^ ((t & 7) << 3)) << 1));
        }
#pragma unroll
        for (int ta = 0; ta < 4; ++ta)
#pragma unroll
          for (int q2 = 0; q2 < 2; ++q2)
            sacc[ta][q2] = mfma16(kf[ta], qf[q2][kk], sacc[ta][q2]);
      }
      __builtin_amdgcn_s_setprio(0);

      if (t0 + 63 > qminw) {
#pragma unroll
        for (int ta = 0; ta < 4; ++ta)
#pragma unroll
          for (int q2 = 0; q2 < 2; ++q2)
#pragma unroll
            for (int r = 0; r < 4; ++r) {
              int t = t0 + ta * 16 + g * 4 + r;
              int q = qminw + q2 * 16 + c;
              if (t > q) sacc[ta][q2][r] = -30000.f;
            }
      }

      float corr[2];
      bool resc = false;
#pragma unroll
      for (int q2 = 0; q2 < 2; ++q2) {
        float mx = -30000.f;
#pragma unroll
        for (int ta = 0; ta < 4; ++ta)
          mx = fmaxf(mx, fmaxf(fmaxf(sacc[ta][q2][0], sacc[ta][q2][1]),
                               fmaxf(sacc[ta][q2][2], sacc[ta][q2][3])));
        mx = fmaxf(mx, __shfl_xor(mx, 16));
        mx = fmaxf(mx, __shfl_xor(mx, 32));
        bool rs = mx > mrun[q2] + 8.0f;
        resc |= rs;
        float mnew = rs ? mx : mrun[q2];
        corr[q2] = fexp2(mrun[q2] - mnew);
        mrun[q2] = mnew;
        float ls = 0.f;
#pragma unroll
        for (int ta = 0; ta < 4; ++ta)
#pragma unroll
          for (int r = 0; r < 4; ++r) {
            float e = fexp2(sacc[ta][q2][r] - mnew);
            sacc[ta][q2][r] = e;
            ls += e;
          }
        ls += __shfl_xor(ls, 16);
        ls += __shfl_xor(ls, 32);
        lrun[q2] = lrun[q2] * corr[q2] + ls;
      }

      if (__any(resc)) {
#pragma unroll
        for (int q2 = 0; q2 < 2; ++q2)
#pragma unroll
          for (int r = 0; r < 4; ++r) {
            float cD = __shfl(corr[q2], (lane & 48) | (((lane >> 4) << 2) + r));
#pragma unroll
            for (int fn = 0; fn < 8; ++fn) accO[q2][fn][r] *= cD;
          }
      }

#pragma unroll
      for (int q2 = 0; q2 < 2; ++q2) {
        int prow = w * 32 + q2 * 16 + c;
#pragma unroll
        for (int ta = 0; ta < 4; ++ta) {
          u16x4 pk;
          pk[0] = f2bf(sacc[ta][q2][0]); pk[1] = f2bf(sacc[ta][q2][1]);
          pk[2] = f2bf(sacc[ta][q2][2]); pk[3] = f2bf(sacc[ta][q2][3]);
          *(u16x4*)(&Plds[prow * 72 + ta * 16 + g * 4]) = pk;
        }
      }
    }

    if (havenext) asm volatile("s_waitcnt vmcnt(2)" ::: "memory");
    else          asm volatile("s_waitcnt vmcnt(0)" ::: "memory");
    __builtin_amdgcn_s_barrier();

    if (t0 <= qmaxw) {
      __builtin_amdgcn_s_setprio(1);
#pragma unroll
      for (int kk = 0; kk < 2; ++kk) {
        bf16x8 pa[2];
#pragma unroll
        for (int q2 = 0; q2 < 2; ++q2)
          pa[q2] = *(const bf16x8*)((const char*)Plds + (w * 32 + q2 * 16 + c) * 144 + (kk * 32 + g * 8) * 2);
#pragma unroll
        for (int fn = 0; fn < 8; ++fn) {
          int d = fn * 16 + c;
          int tt = kk * 32 + g * 8;
          bf16x8 vb = *(const bf16x8*)((const char*)Vlds + d * 128 + ((tt ^ ((d & 7) << 3)) << 1));
#pragma unroll
          for (int q2 = 0; q2 < 2; ++q2)
            accO[q2][fn] = mfma16(pa[q2], vb, accO[q2][fn]);
        }
      }
      __builtin_amdgcn_s_setprio(0);
    }
    __builtin_amdgcn_s_barrier();
  }

  const int b = head >> 4, nh = head & 15;
  float linv[2] = { 1.0f / lrun[0], 1.0f / lrun[1] };
#pragma unroll
  for (int q2 = 0; q2 < 2; ++q2)
#pragma unroll
    for (int r = 0; r < 4; ++r) {
      float inv = __shfl(linv[q2], (lane & 48) | (((lane >> 4) << 2) + r));
      int q = q0w + q2 * 16 + g * 4 + r;
      int m = q * 2 + b;
      int swb = ((m >> 1) & 3) << 3;
#pragma unroll
      for (int fn = 0; fn < 8; ++fn) {
        int h = nh * 128 + fn * 16 + c;
        ctx[(size_t)m * HID + (h ^ swb)] = f2bf(accO[q2][fn][r] * inv);
      }
    }
}

extern "C" void kernel_launch(void* const* d_in, const int* in_sizes, int n_in,
                              void* d_out, int out_size, void* d_ws, size_t ws_size,
                              hipStream_t stream) {
  const float* hidden = (const float*)d_in[0];
  const float* Wqkv = (const float*)d_in[2];
  const float* bqkv = (const float*)d_in[3];
  const float* Wd   = (const float*)d_in[4];
  const float* bd   = (const float*)d_in[5];
  float* out = (float*)d_out;
  char* ws = (char*)d_ws;

  const size_t OFF_HID  = 0;
  const size_t OFF_WQKV = 16777216;
  const size_t OFF_WD   = 41943040;
  const size_t OFF_COS  = 50331648;
  const size_t OFF_SIN  = 50855936;
  const size_t OFF_Q    = 51380224;
  const size_t OFF_K    = 68157440;
  const size_t OFF_VT   = 84934656;
  if (ws_size < 101711872) return;

  unsigned short* hidb  = (unsigned short*)(ws + OFF_HID);
  unsigned short* wqkvb = (unsigned short*)(ws + OFF_WQKV);
  unsigned short* wdb   = (unsigned short*)(ws + OFF_WD);
  float* cosT = (float*)(ws + OFF_COS);
  float* sinT = (float*)(ws + OFF_SIN);
  unsigned short* Qsb = (unsigned short*)(ws + OFF_Q);
  unsigned short* Ksb = (unsigned short*)(ws + OFF_K);
  unsigned short* Vtb = (unsigned short*)(ws + OFF_VT);
  unsigned short* ctxb = hidb;

  prep<<<25088, 256, 0, stream>>>(hidden, Wqkv, Wd, hidb, wqkvb, wdb, cosT, sinT);

  gemm_qkv<<<512, 512, 0, stream>>>(hidb, wqkvb, bqkv, Qsb, Ksb, Vtb, cosT, sinT);
  attn<<<256, 512, 0, stream>>>(Qsb, Ksb, Vtb, ctxb);
  gemm_out<<<256, 512, 0, stream>>>(ctxb, wdb, bd, out);
}

// Round 11
// 231.315 us; speedup vs baseline: 1.5531x; 1.0490x over previous
//
#include <hip/hip_runtime.h>

#define SEQ   2048
#define BATCH 2
#define HID   2048
#define NHEAD 16
#define HDIM  128
#define MTOT  4096
#define KDIM  2048

typedef __attribute__((ext_vector_type(8))) short  bf16x8;
typedef __attribute__((ext_vector_type(4))) float  f32x4;
typedef __attribute__((ext_vector_type(4))) unsigned short u16x4;
typedef __attribute__((ext_vector_type(8))) unsigned short u16x8;

__device__ __forceinline__ unsigned short f2bf(float x) {
  unsigned u = __float_as_uint(x);
  u += 0x7fffu + ((u >> 16) & 1u);
  return (unsigned short)(u >> 16);
}

__device__ __forceinline__ float fexp2(float x) {
  float r;
  asm("v_exp_f32 %0, %1" : "=v"(r) : "v"(x));
  return r;
}

__device__ __forceinline__ void gl_lds16(const void* g, void* l) {
  __builtin_amdgcn_global_load_lds(
      (__attribute__((address_space(1))) void*)g,
      (__attribute__((address_space(3))) void*)l, 16, 0, 0);
}

__device__ __forceinline__ f32x4 mfma16(bf16x8 a, bf16x8 b, f32x4 c) {
  return __builtin_amdgcn_mfma_f32_16x16x32_bf16(a, b, c, 0, 0, 0);
}

// ---------------------------------------------------------------------------
// Fused prep: fp32->bf16, K-granule swizzle widened to 3 bits for the BK=64
// GEMMs: element (r,k) -> r*2048 + (k ^ (((r>>1)&7)<<3))  (permutes 8-elem
// granules within each 64-elem k-block; read slot (khalf*4+g)^((r>>1)&7)
// spreads 16 consecutive rows over all 32 banks at 128B row pitch).
// + RoPE cos/sin table.
// ---------------------------------------------------------------------------
__global__ __launch_bounds__(256, 8)
void prep(const float* __restrict__ hidden, const float* __restrict__ Wqkv,
          const float* __restrict__ Wd,
          unsigned short* __restrict__ hidb, unsigned short* __restrict__ wqkvb,
          unsigned short* __restrict__ wdb,
          float* __restrict__ cosT, float* __restrict__ sinT) {
  int bid = blockIdx.x;
  if (bid < 24576) {
    const float* src; unsigned short* dst; int lb;
    if (bid < 8192)       { src = hidden; dst = hidb;  lb = bid; }
    else if (bid < 20480) { src = Wqkv;   dst = wqkvb; lb = bid - 8192; }
    else                  { src = Wd;     dst = wdb;   lb = bid - 20480; }
    int i = lb * 256 + threadIdx.x;
    int base = i << 2;
    int r = base >> 11, k = base & 2047;
    f32x4 v = *(const f32x4*)(src + base);
    int kp = k ^ (((r >> 1) & 7) << 3);
    u16x4 o;
    o[0] = f2bf(v[0]); o[1] = f2bf(v[1]); o[2] = f2bf(v[2]); o[3] = f2bf(v[3]);
    *(u16x4*)(dst + (size_t)r * 2048 + kp) = o;
  } else {
    int idx = (bid - 24576) * 256 + threadIdx.x;   // 2048*64
    int s = idx >> 6, i = idx & 63;
    float inv = powf(1e-4f, (float)i * (1.0f / 64.0f));
    float a = (float)s * inv;
    cosT[idx] = cosf(a);
    sinT[idx] = sinf(a);
  }
}

// ---------------------------------------------------------------------------
// QKV GEMM: 128x384 tile, BK=64 (32 K-tiles -> HALF the barrier/drain events
// of the r6 BK=32 version), grid 512 = 2 full rounds, 8 waves = 2M x 4N.
// LDS 144 KiB: A ring-3 (3 x 16K) @0, B ring-2 (2 x 48K) @49152.
// Per tile: issue STG_B(T+1) [6 ops] then STG_A(T+2) [2 ops]; two khalf
// {10 ds_read_b128 + 24 MFMA} groups; end-of-tile vmcnt(2) leaves only
// A(T+2) in flight => B(T+1)/A(T+1) landed before next tile reads them.
// Rows are 128B; bank-conflict-free via the 3-bit granule swizzle.
// Epilogue: Q/K RoPE + swizzled stores; V transposed via LDS (fused).
// ---------------------------------------------------------------------------
__global__ __launch_bounds__(512, 2)
void gemm_qkv(const unsigned short* __restrict__ A,
              const unsigned short* __restrict__ Bt,
              const float* __restrict__ bias,
              unsigned short* __restrict__ Qs,
              unsigned short* __restrict__ Ks,
              unsigned short* __restrict__ Vt,
              const float* __restrict__ cosT,
              const float* __restrict__ sinT)
{
  __shared__ alignas(16) char lds[147456];   // 144 KiB
  const int tid = threadIdx.x;
  const int wid = tid >> 6, lane = tid & 63, g = lane >> 4, c = lane & 15;
  const int wr = wid >> 2, wc = wid & 3;

  const int bid = blockIdx.x;
  const int swz = (bid & 7) * 64 + (bid >> 3);
  const int nblk = swz & 15, mblk = swz >> 4;
  const int m0 = mblk << 7;
  const int n0 = nblk * 384;
  const int nh = nblk;

  char* ldsb = (char*)lds;
  const int sw = c >> 1;   // (row>>1)&7 for row = base + c, base % 16 == 0
  const char* ldsA0 = ldsb + (wr * 64 + c) * 128 + ((g ^ sw) << 4);
  const char* ldsA1 = ldsb + (wr * 64 + c) * 128 + (((4 + g) ^ sw) << 4);
  const char* ldsB0 = ldsb + 49152 + (wc * 16 + c) * 128 + ((g ^ sw) << 4);
  const char* ldsB1 = ldsb + 49152 + (wc * 16 + c) * 128 + (((4 + g) ^ sw) << 4);

  const char* gA = (const char*)A  + (size_t)(m0 + (tid >> 3)) * 4096 + (tid & 7) * 16;
  const char* gB = (const char*)Bt + (size_t)(n0 + (tid >> 3)) * 4096 + (tid & 7) * 16;
  char* lA = ldsb + tid * 16;
  char* lB = ldsb + 49152 + tid * 16;

#define STG_A(T, BUF) do { const char* _g = gA + (T) * 128; char* _l = lA + (BUF) * 16384; \
    gl_lds16(_g, _l); gl_lds16(_g + 262144, _l + 8192); } while (0)
#define STG_B(T, BUF) do { const char* _g = gB + (T) * 128; char* _l = lB + (BUF) * 49152; \
    gl_lds16(_g, _l);           gl_lds16(_g + 262144, _l + 8192);   \
    gl_lds16(_g + 524288, _l + 16384); gl_lds16(_g + 786432, _l + 24576); \
    gl_lds16(_g + 1048576, _l + 32768); gl_lds16(_g + 1310720, _l + 40960); } while (0)

  f32x4 acc[4][6];
#pragma unroll
  for (int i = 0; i < 4; ++i)
#pragma unroll
    for (int j = 0; j < 6; ++j) {
      acc[i][j][0] = 0.f; acc[i][j][1] = 0.f; acc[i][j][2] = 0.f; acc[i][j][3] = 0.f;
    }

  bf16x8 a[4], b[6];
  const int NT = KDIM / 64;   // 32

#define HALF(PA, PB, SA, SB) do {                                           \
    _Pragma("unroll")                                                       \
    for (int mf = 0; mf < 4; ++mf)                                          \
      a[mf] = *(const bf16x8*)(PA + (SA) * 16384 + mf * 2048);              \
    _Pragma("unroll")                                                       \
    for (int nl = 0; nl < 6; ++nl)                                          \
      b[nl] = *(const bf16x8*)(PB + (SB) * 49152 + nl * 8192);              \
    __builtin_amdgcn_s_setprio(1);                                          \
    _Pragma("unroll")                                                       \
    for (int mf = 0; mf < 4; ++mf)                                          \
      _Pragma("unroll")                                                     \
      for (int nl = 0; nl < 6; ++nl)                                        \
        acc[mf][nl] = mfma16(a[mf], b[nl], acc[mf][nl]);                    \
    __builtin_amdgcn_s_setprio(0);                                          \
  } while (0)

#define TILE(T, SA, SB) do {                                                \
    if ((T) + 1 < NT) { STG_B((T) + 1, ((T) + 1) & 1); }                    \
    if ((T) + 2 < NT) { STG_A((T) + 2, ((T) + 2) % 3); }                    \
    HALF(ldsA0, ldsB0, SA, SB);                                             \
    HALF(ldsA1, ldsB1, SA, SB);                                             \
    if ((T) + 2 < NT) { asm volatile("s_waitcnt vmcnt(2)" ::: "memory"); }  \
    else              { asm volatile("s_waitcnt vmcnt(0)" ::: "memory"); }  \
    __builtin_amdgcn_s_barrier();                                           \
  } while (0)

  // Prologue: B(0) 6 ops, A(0) 2 ops, A(1) 2 ops; vmcnt(2) -> B0,A0 landed.
  STG_B(0, 0); STG_A(0, 0); STG_A(1, 1);
  asm volatile("s_waitcnt vmcnt(2)" ::: "memory");
  __builtin_amdgcn_s_barrier();

  for (int t = 0; t < 30; t += 6) {   // slot pattern period 6 (lcm(3,2))
    TILE(t + 0, 0, 0);
    TILE(t + 1, 1, 1);
    TILE(t + 2, 2, 0);
    TILE(t + 3, 0, 1);
    TILE(t + 4, 1, 0);
    TILE(t + 5, 2, 1);
  }
  TILE(30, 0, 0);
  TILE(31, 1, 1);

  // ---- epilogue: bias + RoPE (Q/K) and fused V transpose ----
  const float qsc = 0.08838834764831845f * 1.4426950408889634f; // 1/sqrt(128)*log2(e)
  const int dl = wc * 16 + c;   // 0..63
  unsigned short* Vtmp = (unsigned short*)ldsb;   // [2][64][136] = 34 KiB
  const int s0 = m0 >> 1;
#pragma unroll
  for (int ar = 0; ar < 4; ++ar) {
#pragma unroll
    for (int rr = 0; rr < 4; ++rr) {
      int m = m0 + wr * 64 + ar * 16 + g * 4 + rr;
      int s = m >> 1, bb = m & 1;
      size_t plane = (size_t)(bb * NHEAD + nh) * (SEQ * HDIM);
      int swb = (s & 7) << 3;
      float co = cosT[s * 64 + dl], si = sinT[s * 64 + dl];
      {
        float xl = acc[ar][0][rr] + bias[n0 + dl];
        float xr = acc[ar][1][rr] + bias[n0 + 64 + dl];
        Qs[plane + (size_t)s * HDIM + (dl ^ swb)]        = f2bf((co * xl - si * xr) * qsc);
        Qs[plane + (size_t)s * HDIM + ((dl + 64) ^ swb)] = f2bf((si * xl + co * xr) * qsc);
      }
      {
        float xl = acc[ar][2][rr] + bias[n0 + 128 + dl];
        float xr = acc[ar][3][rr] + bias[n0 + 192 + dl];
        Ks[plane + (size_t)s * HDIM + (dl ^ swb)]        = f2bf(co * xl - si * xr);
        Ks[plane + (size_t)s * HDIM + ((dl + 64) ^ swb)] = f2bf(si * xl + co * xr);
      }
      {
        int sloc = s - s0;
        Vtmp[(bb * 64 + sloc) * 136 + dl]      = f2bf(acc[ar][4][rr] + bias[n0 + 256 + dl]);
        Vtmp[(bb * 64 + sloc) * 136 + dl + 64] = f2bf(acc[ar][5][rr] + bias[n0 + 320 + dl]);
      }
    }
  }
  __syncthreads();
  {
    int b2 = tid >> 8, r = tid & 255;
    int d = r >> 1, half = r & 1;
    size_t planeV = (size_t)(b2 * NHEAD + nh) * (SEQ * HDIM);
    unsigned short* dstp = Vt + planeV + (size_t)d * SEQ + s0;
    int swb = (d & 7) << 3;
#pragma unroll
    for (int gg = 0; gg < 4; ++gg) {
      u16x8 v;
#pragma unroll
      for (int e = 0; e < 8; ++e)
        v[e] = Vtmp[(b2 * 64 + half * 32 + gg * 8 + e) * 136 + d];
      int tloc = half * 32 + gg * 8;
      *(u16x8*)(dstp + (tloc ^ swb)) = v;
    }
  }
#undef TILE
#undef HALF
#undef STG_A
#undef STG_B
}

// ---------------------------------------------------------------------------
// Dense projection GEMM: 128x256 tile, BK=64, grid 256 = 1 full round.
// LDS 144 KiB: A ring-3 (3 x 16K) @0, B ring-3 (3 x 32K) @49152.
// Per tile: stage T+2 (B 4 ops + A 2 ops); 2 khalf groups of
// {8 ds_read + 16 MFMA}; end-of-tile vmcnt(6) leaves T+2's 6 in flight.
// ---------------------------------------------------------------------------
__global__ __launch_bounds__(512, 2)
void gemm_out(const unsigned short* __restrict__ A,
              const unsigned short* __restrict__ Bt,
              const float* __restrict__ bias,
              float* __restrict__ Cout)
{
  __shared__ alignas(16) char lds[147456];   // 144 KiB
  const int tid = threadIdx.x;
  const int wid = tid >> 6, lane = tid & 63, g = lane >> 4, c = lane & 15;
  const int wr = wid >> 2, wc = wid & 3;

  const int bid = blockIdx.x;
  const int swz = (bid & 7) * 32 + (bid >> 3);
  const int nblk = swz >> 5, mblk = swz & 31;
  const int m0 = mblk << 7, n0 = nblk << 8;

  char* ldsb = (char*)lds;
  const int sw = c >> 1;
  const char* ldsA0 = ldsb + (wr * 64 + c) * 128 + ((g ^ sw) << 4);
  const char* ldsA1 = ldsb + (wr * 64 + c) * 128 + (((4 + g) ^ sw) << 4);
  const char* ldsB0 = ldsb + 49152 + (wc * 64 + c) * 128 + ((g ^ sw) << 4);
  const char* ldsB1 = ldsb + 49152 + (wc * 64 + c) * 128 + (((4 + g) ^ sw) << 4);

  const char* gA = (const char*)A  + (size_t)(m0 + (tid >> 3)) * 4096 + (tid & 7) * 16;
  const char* gB = (const char*)Bt + (size_t)(n0 + (tid >> 3)) * 4096 + (tid & 7) * 16;
  char* lA = ldsb + tid * 16;
  char* lB = ldsb + 49152 + tid * 16;

#define STG_A(T, BUF) do { const char* _g = gA + (T) * 128; char* _l = lA + (BUF) * 16384; \
    gl_lds16(_g, _l); gl_lds16(_g + 262144, _l + 8192); } while (0)
#define STG_B(T, BUF) do { const char* _g = gB + (T) * 128; char* _l = lB + (BUF) * 32768; \
    gl_lds16(_g, _l);           gl_lds16(_g + 262144, _l + 8192);   \
    gl_lds16(_g + 524288, _l + 16384); gl_lds16(_g + 786432, _l + 24576); } while (0)

  f32x4 acc[4][4];
#pragma unroll
  for (int i = 0; i < 4; ++i)
#pragma unroll
    for (int j = 0; j < 4; ++j) {
      acc[i][j][0] = 0.f; acc[i][j][1] = 0.f; acc[i][j][2] = 0.f; acc[i][j][3] = 0.f;
    }

  bf16x8 a[4], b[4];
  const int NT = KDIM / 64;   // 32

#define HALF(PA, PB, S) do {                                                \
    _Pragma("unroll")                                                       \
    for (int mf = 0; mf < 4; ++mf)                                          \
      a[mf] = *(const bf16x8*)(PA + (S) * 16384 + mf * 2048);               \
    _Pragma("unroll")                                                       \
    for (int nl = 0; nl < 4; ++nl)                                          \
      b[nl] = *(const bf16x8*)(PB + (S) * 32768 + nl * 2048);               \
    __builtin_amdgcn_s_setprio(1);                                          \
    _Pragma("unroll")                                                       \
    for (int mf = 0; mf < 4; ++mf)                                          \
      _Pragma("unroll")                                                     \
      for (int nl = 0; nl < 4; ++nl)                                        \
        acc[mf][nl] = mfma16(a[mf], b[nl], acc[mf][nl]);                    \
    __builtin_amdgcn_s_setprio(0);                                          \
  } while (0)

#define TILE(T, S) do {                                                     \
    if ((T) + 2 < NT) { STG_B((T) + 2, ((T) + 2) % 3); STG_A((T) + 2, ((T) + 2) % 3); } \
    HALF(ldsA0, ldsB0, S);                                                  \
    HALF(ldsA1, ldsB1, S);                                                  \
    if ((T) + 2 < NT) { asm volatile("s_waitcnt vmcnt(6)" ::: "memory"); }  \
    else              { asm volatile("s_waitcnt vmcnt(0)" ::: "memory"); }  \
    __builtin_amdgcn_s_barrier();                                           \
  } while (0)

  STG_B(0, 0); STG_A(0, 0);
  STG_B(1, 1); STG_A(1, 1);
  asm volatile("s_waitcnt vmcnt(6)" ::: "memory");
  __builtin_amdgcn_s_barrier();

  for (int t = 0; t < 30; t += 3) {
    TILE(t, 0);
    TILE(t + 1, 1);
    TILE(t + 2, 2);
  }
  TILE(30, 0);
  TILE(31, 1);

#pragma unroll
  for (int mf = 0; mf < 4; ++mf)
#pragma unroll
    for (int rr = 0; rr < 4; ++rr) {
      int m = m0 + wr * 64 + mf * 16 + g * 4 + rr;
#pragma unroll
      for (int nl = 0; nl < 4; ++nl) {
        int n = n0 + wc * 64 + nl * 16 + c;
        Cout[(size_t)m * HID + n] = acc[mf][nl][rr] + bias[n];
      }
    }
#undef TILE
#undef HALF
#undef STG_A
#undef STG_B
}

// ---------------------------------------------------------------------------
// Flash attention (round-9 pair-scheduled version, unchanged)
// ---------------------------------------------------------------------------
__global__ __launch_bounds__(512, 2)
void attn(const unsigned short* __restrict__ Qs,
          const unsigned short* __restrict__ Ks,
          const unsigned short* __restrict__ Vt,
          unsigned short* __restrict__ ctx)
{
  __shared__ alignas(16) unsigned short Klds[2][64 * 128];   // 2 x 16 KiB
  __shared__ alignas(16) unsigned short Vlds[128 * 64];      // 16 KiB
  __shared__ alignas(16) unsigned short Plds[256 * 72];      // 36 KiB
  const int tid = threadIdx.x;
  const int w = tid >> 6, lane = tid & 63, g = lane >> 4, c = lane & 15;
  const int bid = blockIdx.x;
  const int head = bid & 31;
  const int j = bid >> 5;                 // 0..7
  const int qbh = 15 - j;
  const int q0w = (w < 4) ? ((qbh << 7) + w * 32) : ((j << 7) + (w - 4) * 32);
  const size_t plane = (size_t)head * (SEQ * HDIM);
  const unsigned short* Qp = Qs + plane;

  bf16x8 qf[2][4];
#pragma unroll
  for (int q2 = 0; q2 < 2; ++q2) {
    int s = q0w + q2 * 16 + c;
    int swb = (s & 7) << 3;
#pragma unroll
    for (int kk = 0; kk < 4; ++kk) {
      int d0 = kk * 32 + g * 8;
      qf[q2][kk] = *(const bf16x8*)(Qp + (size_t)s * HDIM + (d0 ^ swb));
    }
  }

  f32x4 accO[2][8];
#pragma unroll
  for (int i = 0; i < 2; ++i)
#pragma unroll
    for (int jj = 0; jj < 8; ++jj) {
      accO[i][jj][0] = 0.f; accO[i][jj][1] = 0.f; accO[i][jj][2] = 0.f; accO[i][jj][3] = 0.f;
    }
  float mrun[2] = { -1e30f, -1e30f };
  float lrun[2] = { 0.f, 0.f };

  const char* Kg = (const char*)(Ks + plane) + (tid >> 4) * 256 + (tid & 15) * 16;
  const char* Vg = (const char*)(Vt + plane) + (size_t)(tid >> 3) * 4096 + (tid & 7) * 16;

  const int ntiles = (qbh << 1) + 2;
  const int qminw = q0w;
  const int qmaxw = q0w + 31;

  gl_lds16(Kg,        (char*)Klds[0] + tid * 16);
  gl_lds16(Kg + 8192, (char*)Klds[0] + tid * 16 + 8192);

  for (int kt = 0; kt < ntiles; ++kt) {
    const int t0 = kt << 6;
    const bool havenext = (kt + 1 < ntiles);

    gl_lds16(Vg + t0 * 2,          (char*)Vlds + tid * 16);
    gl_lds16(Vg + t0 * 2 + 262144, (char*)Vlds + tid * 16 + 8192);
    if (havenext) {
      char* kd = (char*)Klds[(kt + 1) & 1] + tid * 16;
      gl_lds16(Kg + (size_t)(t0 + 64) * 256,        kd);
      gl_lds16(Kg + (size_t)(t0 + 64) * 256 + 8192, kd + 8192);
    }
    if (havenext) asm volatile("s_waitcnt vmcnt(4)" ::: "memory");
    else          asm volatile("s_waitcnt vmcnt(2)" ::: "memory");
    __builtin_amdgcn_s_barrier();

    if (t0 <= qmaxw) {
      const char* Kb = (const char*)Klds[kt & 1];
      f32x4 sacc[4][2];
#pragma unroll
      for (int i = 0; i < 4; ++i)
#pragma unroll
        for (int jj = 0; jj < 2; ++jj) {
          sacc[i][jj][0] = 0.f; sacc[i][jj][1] = 0.f; sacc[i][jj][2] = 0.f; sacc[i][jj][3] = 0.f;
        }
      __builtin_amdgcn_s_setprio(1);
#pragma unroll
      for (int kk = 0; kk < 4; ++kk) {
        bf16x8 kf[4];
#pragma unroll
        for (int ta = 0; ta < 4; ++ta) {
          int t = ta * 16 + c;
          int d0 = kk * 32 + g * 8;
          kf[ta] = *(const bf16x8*)(Kb + t * 256 + ((d0 ^ ((t & 7) << 3)) << 1));
        }
#pragma unroll
        for (int ta = 0; ta < 4; ++ta)
#pragma unroll
          for (int q2 = 0; q2 < 2; ++q2)
            sacc[ta][q2] = mfma16(kf[ta], qf[q2][kk], sacc[ta][q2]);
      }
      __builtin_amdgcn_s_setprio(0);

      if (t0 + 63 > qminw) {
#pragma unroll
        for (int ta = 0; ta < 4; ++ta)
#pragma unroll
          for (int q2 = 0; q2 < 2; ++q2)
#pragma unroll
            for (int r = 0; r < 4; ++r) {
              int t = t0 + ta * 16 + g * 4 + r;
              int q = qminw + q2 * 16 + c;
              if (t > q) sacc[ta][q2][r] = -30000.f;
            }
      }

      float corr[2];
      bool resc = false;
#pragma unroll
      for (int q2 = 0; q2 < 2; ++q2) {
        float mx = -30000.f;
#pragma unroll
        for (int ta = 0; ta < 4; ++ta)
          mx = fmaxf(mx, fmaxf(fmaxf(sacc[ta][q2][0], sacc[ta][q2][1]),
                               fmaxf(sacc[ta][q2][2], sacc[ta][q2][3])));
        mx = fmaxf(mx, __shfl_xor(mx, 16));
        mx = fmaxf(mx, __shfl_xor(mx, 32));
        bool rs = mx > mrun[q2] + 8.0f;
        resc |= rs;
        float mnew = rs ? mx : mrun[q2];
        corr[q2] = fexp2(mrun[q2] - mnew);
        mrun[q2] = mnew;
        float ls = 0.f;
#pragma unroll
        for (int ta = 0; ta < 4; ++ta)
#pragma unroll
          for (int r = 0; r < 4; ++r) {
            float e = fexp2(sacc[ta][q2][r] - mnew);
            sacc[ta][q2][r] = e;
            ls += e;
          }
        ls += __shfl_xor(ls, 16);
        ls += __shfl_xor(ls, 32);
        lrun[q2] = lrun[q2] * corr[q2] + ls;
      }

      if (__any(resc)) {
#pragma unroll
        for (int q2 = 0; q2 < 2; ++q2)
#pragma unroll
          for (int r = 0; r < 4; ++r) {
            float cD = __shfl(corr[q2], (lane & 48) | (((lane >> 4) << 2) + r));
#pragma unroll
            for (int fn = 0; fn < 8; ++fn) accO[q2][fn][r] *= cD;
          }
      }

#pragma unroll
      for (int q2 = 0; q2 < 2; ++q2) {
        int prow = w * 32 + q2 * 16 + c;
#pragma unroll
        for (int ta = 0; ta < 4; ++ta) {
          u16x4 pk;
          pk[0] = f2bf(sacc[ta][q2][0]); pk[1] = f2bf(sacc[ta][q2][1]);
          pk[2] = f2bf(sacc[ta][q2][2]); pk[3] = f2bf(sacc[ta][q2][3]);
          *(u16x4*)(&Plds[prow * 72 + ta * 16 + g * 4]) = pk;
        }
      }
    }

    if (havenext) asm volatile("s_waitcnt vmcnt(2)" ::: "memory");
    else          asm volatile("s_waitcnt vmcnt(0)" ::: "memory");
    __builtin_amdgcn_s_barrier();

    if (t0 <= qmaxw) {
      __builtin_amdgcn_s_setprio(1);
#pragma unroll
      for (int kk = 0; kk < 2; ++kk) {
        bf16x8 pa[2];
#pragma unroll
        for (int q2 = 0; q2 < 2; ++q2)
          pa[q2] = *(const bf16x8*)((const char*)Plds + (w * 32 + q2 * 16 + c) * 144 + (kk * 32 + g * 8) * 2);
#pragma unroll
        for (int fn = 0; fn < 8; ++fn) {
          int d = fn * 16 + c;
          int tt = kk * 32 + g * 8;
          bf16x8 vb = *(const bf16x8*)((const char*)Vlds + d * 128 + ((tt ^ ((d & 7) << 3)) << 1));
#pragma unroll
          for (int q2 = 0; q2 < 2; ++q2)
            accO[q2][fn] = mfma16(pa[q2], vb, accO[q2][fn]);
        }
      }
      __builtin_amdgcn_s_setprio(0);
    }
    __builtin_amdgcn_s_barrier();
  }

  const int b = head >> 4, nh = head & 15;
  float linv[2] = { 1.0f / lrun[0], 1.0f / lrun[1] };
#pragma unroll
  for (int q2 = 0; q2 < 2; ++q2)
#pragma unroll
    for (int r = 0; r < 4; ++r) {
      float inv = __shfl(linv[q2], (lane & 48) | (((lane >> 4) << 2) + r));
      int q = q0w + q2 * 16 + g * 4 + r;
      int m = q * 2 + b;
      int swb = ((m >> 1) & 7) << 3;
#pragma unroll
      for (int fn = 0; fn < 8; ++fn) {
        int h = nh * 128 + fn * 16 + c;
        ctx[(size_t)m * HID + (h ^ swb)] = f2bf(accO[q2][fn][r] * inv);
      }
    }
}

extern "C" void kernel_launch(void* const* d_in, const int* in_sizes, int n_in,
                              void* d_out, int out_size, void* d_ws, size_t ws_size,
                              hipStream_t stream) {
  const float* hidden = (const float*)d_in[0];
  const float* Wqkv = (const float*)d_in[2];
  const float* bqkv = (const float*)d_in[3];
  const float* Wd   = (const float*)d_in[4];
  const float* bd   = (const float*)d_in[5];
  float* out = (float*)d_out;
  char* ws = (char*)d_ws;

  const size_t OFF_HID  = 0;
  const size_t OFF_WQKV = 16777216;
  const size_t OFF_WD   = 41943040;
  const size_t OFF_COS  = 50331648;
  const size_t OFF_SIN  = 50855936;
  const size_t OFF_Q    = 51380224;
  const size_t OFF_K    = 68157440;
  const size_t OFF_VT   = 84934656;
  if (ws_size < 101711872) return;

  unsigned short* hidb  = (unsigned short*)(ws + OFF_HID);
  unsigned short* wqkvb = (unsigned short*)(ws + OFF_WQKV);
  unsigned short* wdb   = (unsigned short*)(ws + OFF_WD);
  float* cosT = (float*)(ws + OFF_COS);
  float* sinT = (float*)(ws + OFF_SIN);
  unsigned short* Qsb = (unsigned short*)(ws + OFF_Q);
  unsigned short* Ksb = (unsigned short*)(ws + OFF_K);
  unsigned short* Vtb = (unsigned short*)(ws + OFF_VT);
  unsigned short* ctxb = hidb;

  prep<<<25088, 256, 0, stream>>>(hidden, Wqkv, Wd, hidb, wqkvb, wdb, cosT, sinT);

  gemm_qkv<<<512, 512, 0, stream>>>(hidb, wqkvb, bqkv, Qsb, Ksb, Vtb, cosT, sinT);
  attn<<<256, 512, 0, stream>>>(Qsb, Ksb, Vtb, ctxb);
  gemm_out<<<256, 512, 0, stream>>>(ctxb, wdb, bd, out);
}